// Round 1
// baseline (972.588 us; speedup 1.0000x reference)
//
#include <hip/hip_runtime.h>
#include <math.h>

#define YAT_EPS (1.0f / 137.0f)

// Logical sizes (fixed by the problem): B=2, T=1024, C=1024.
// Attention (faithful to the reference's transpose): 64 "heads" (d axis),
// per-head dim 16 (h axis), causal, T=1024.

// ---------------------------------------------------------------------------
// k2[f] = sum_c W[c][f]^2  (column sums of squares), split over K with atomics
// ---------------------------------------------------------------------------
__global__ __launch_bounds__(256) void colsumsq_kernel(
    const float* __restrict__ W, float* __restrict__ k2, int K, int N)
{
    int f = blockIdx.x * 256 + threadIdx.x;
    int chunk = K / gridDim.y;
    int c0 = blockIdx.y * chunk;
    float s = 0.0f;
    for (int c = c0; c < c0 + chunk; ++c) {
        float w = W[(size_t)c * N + f];
        s = fmaf(w, w, s);
    }
    atomicAdd(&k2[f], s);
}

// ---------------------------------------------------------------------------
// out[row] = sum_k X[row][k]^2 ; one wave (64 lanes) per row, ncols % 256 == 0
// ---------------------------------------------------------------------------
__global__ __launch_bounds__(256) void rowsumsq_kernel(
    const float* __restrict__ X, float* __restrict__ out, int ncols)
{
    int wave = threadIdx.x >> 6;
    int lane = threadIdx.x & 63;
    int row = blockIdx.x * 4 + wave;
    const float* p = X + (size_t)row * ncols;
    float s = 0.0f;
    for (int k = lane * 4; k < ncols; k += 256) {
        float4 v = *(const float4*)(p + k);
        s = fmaf(v.x, v.x, s);
        s = fmaf(v.y, v.y, s);
        s = fmaf(v.z, v.z, s);
        s = fmaf(v.w, v.w, s);
    }
    #pragma unroll
    for (int off = 32; off > 0; off >>= 1) s += __shfl_down(s, off, 64);
    if (lane == 0) out[row] = s;
}

// ---------------------------------------------------------------------------
// Fused YAT dense: out = (A.W)^2 / (x2 + k2 - 2 A.W + eps) * scale + bias
// 64x64 tile, BK=16, 256 threads, 4x4 per thread, fp32.
// MODE 0: standard row-major store.
// MODE 1: scatter into qkvT[b][s][d][t][h] (h contiguous, 16 per row) where
//         m = b*1024+t and n = s*1024 + h*64 + d. All dims divide evenly.
// ---------------------------------------------------------------------------
template <int MODE>
__global__ __launch_bounds__(256) void gemm_yat_kernel(
    const float* __restrict__ A, const float* __restrict__ W,
    const float* __restrict__ bias, const float* __restrict__ x2,
    const float* __restrict__ k2, const float* __restrict__ alphap,
    float* __restrict__ out, int M, int N, int K, float scale_base)
{
    __shared__ float As[16][68];  // [k][m], pad 68 to break write conflicts
    __shared__ float Bs[16][64];  // [k][n]

    const int tid = threadIdx.x;
    const int tx = tid & 15, ty = tid >> 4;
    const int m0 = blockIdx.y * 64, n0 = blockIdx.x * 64;

    const int arow = tid >> 2, ac4 = (tid & 3) * 4;
    const int brow = tid >> 4, bc4 = (tid & 15) * 4;
    const float* Ap = A + (size_t)(m0 + arow) * K + ac4;
    const float* Wp = W + (size_t)brow * N + n0 + bc4;

    float acc[4][4];
    #pragma unroll
    for (int e = 0; e < 4; ++e)
        #pragma unroll
        for (int j = 0; j < 4; ++j) acc[e][j] = 0.0f;

    for (int k0 = 0; k0 < K; k0 += 16) {
        float4 av = *(const float4*)(Ap + k0);
        float4 bv = *(const float4*)(Wp + (size_t)k0 * N);
        __syncthreads();
        As[ac4 + 0][arow] = av.x;
        As[ac4 + 1][arow] = av.y;
        As[ac4 + 2][arow] = av.z;
        As[ac4 + 3][arow] = av.w;
        *(float4*)&Bs[brow][bc4] = bv;
        __syncthreads();
        #pragma unroll
        for (int kk = 0; kk < 16; ++kk) {
            float4 a = *(const float4*)&As[kk][ty * 4];
            float4 b = *(const float4*)&Bs[kk][tx * 4];
            float ar[4] = {a.x, a.y, a.z, a.w};
            float br[4] = {b.x, b.y, b.z, b.w};
            #pragma unroll
            for (int e = 0; e < 4; ++e)
                #pragma unroll
                for (int j = 0; j < 4; ++j)
                    acc[e][j] = fmaf(ar[e], br[j], acc[e][j]);
        }
    }

    const float scale = powf(scale_base, alphap[0]);
    #pragma unroll
    for (int e = 0; e < 4; ++e) {
        const int m = m0 + ty * 4 + e;
        const float xx = x2[m];
        float r[4];
        #pragma unroll
        for (int j = 0; j < 4; ++j) {
            const int n = n0 + tx * 4 + j;
            const float y = acc[e][j];
            const float den = xx + k2[n] - 2.0f * y + YAT_EPS;
            r[j] = y * y / den * scale + bias[n];
        }
        if (MODE == 0) {
            *(float4*)&out[(size_t)m * N + n0 + tx * 4] =
                make_float4(r[0], r[1], r[2], r[3]);
        } else {
            const int b = m >> 10, t = m & 1023;
            #pragma unroll
            for (int j = 0; j < 4; ++j) {
                const int f = n0 + tx * 4 + j;
                const int s = f >> 10, hh = (f >> 6) & 15, d = f & 63;
                out[((size_t)(((b * 3 + s) * 64 + d) * 1024 + t)) * 16 + hh] = r[j];
            }
        }
    }
}

// ---------------------------------------------------------------------------
// Flash-style causal YAT attention over qkvT[b][s][d][t][h].
// Block = 128 threads: dl = tid&15 (d within group of 16), ir = tid>>4 (0..7),
// each thread owns rows i0+ir and i0+8+ir (shares LDS k/v reads).
// Grid = B(2) * dgroups(4) * itiles(64) = 512 blocks.
// score s = dot^2/(q2+k2-2dot+eps)*inv_scale >= 0; online softmax with
// deferred rescale; masked (j>i) entries contribute exactly 0.
// ---------------------------------------------------------------------------
__global__ __launch_bounds__(128) void yat_attention_kernel(
    const float* __restrict__ qkvT, const float* __restrict__ alphap,
    float* __restrict__ attn_out)
{
    __shared__ float kS[16][16][20];  // [jj][d_local][h], pitch 20 (16B-aligned)
    __shared__ float vS[16][16][20];

    const int tid = threadIdx.x;
    const int dl = tid & 15;
    const int ir = tid >> 4;  // 0..7
    const int bid = blockIdx.x;
    const int itile = bid & 63;
    const int dg = (bid >> 6) & 3;
    const int b = bid >> 8;
    const int d = dg * 16 + dl;
    const int i0 = itile * 16;
    const int i_a = i0 + ir;
    const int i_b = i0 + 8 + ir;

    const float inv_scale = powf(64.0f / log1pf(64.0f), alphap[0]);

    const size_t plane = 1024 * 16;  // elements per (b,s,d) plane
    const float* qpl = qkvT + ((size_t)((b * 3 + 0) * 64 + d)) * plane;
    const float* kpl0 = qkvT + ((size_t)((b * 3 + 1) * 64 + dg * 16)) * plane;
    const float* vpl0 = qkvT + ((size_t)((b * 3 + 2) * 64 + dg * 16)) * plane;

    float qa[16], qb[16];
    {
        const float* pa = qpl + (size_t)i_a * 16;
        const float* pb = qpl + (size_t)i_b * 16;
        #pragma unroll
        for (int h4 = 0; h4 < 4; ++h4) {
            float4 va = *(const float4*)(pa + h4 * 4);
            float4 vb = *(const float4*)(pb + h4 * 4);
            qa[h4 * 4 + 0] = va.x; qa[h4 * 4 + 1] = va.y;
            qa[h4 * 4 + 2] = va.z; qa[h4 * 4 + 3] = va.w;
            qb[h4 * 4 + 0] = vb.x; qb[h4 * 4 + 1] = vb.y;
            qb[h4 * 4 + 2] = vb.z; qb[h4 * 4 + 3] = vb.w;
        }
    }
    float q2a = 0.0f, q2b = 0.0f;
    #pragma unroll
    for (int h = 0; h < 16; ++h) {
        q2a = fmaf(qa[h], qa[h], q2a);
        q2b = fmaf(qb[h], qb[h], q2b);
    }

    float ma = -INFINITY, la = 0.0f;
    float mb_ = -INFINITY, lb = 0.0f;
    float oa[16], ob[16];
    #pragma unroll
    for (int h = 0; h < 16; ++h) { oa[h] = 0.0f; ob[h] = 0.0f; }

    const int ntiles = itile + 1;
    for (int jt = 0; jt < ntiles; ++jt) {
        const int j0 = jt * 16;
        __syncthreads();
        #pragma unroll
        for (int it = 0; it < 8; ++it) {
            int f4 = it * 128 + tid;          // 0..1023
            int jj = f4 >> 6;
            int rem = f4 & 63;
            int dd = rem >> 2;
            int h4 = rem & 3;
            size_t goff = (size_t)dd * plane + (size_t)(j0 + jj) * 16 + h4 * 4;
            float4 kv = *(const float4*)(kpl0 + goff);
            float4 vv = *(const float4*)(vpl0 + goff);
            *(float4*)&kS[jj][dd][h4 * 4] = kv;
            *(float4*)&vS[jj][dd][h4 * 4] = vv;
        }
        __syncthreads();
        for (int jj = 0; jj < 16; ++jj) {
            const int j = j0 + jj;
            if (j > i_b) break;  // per-lane exit; all lanes rejoin at tile barrier
            float kreg[16];
            #pragma unroll
            for (int h4 = 0; h4 < 4; ++h4) {
                float4 kv = *(const float4*)&kS[jj][dl][h4 * 4];
                kreg[h4 * 4 + 0] = kv.x; kreg[h4 * 4 + 1] = kv.y;
                kreg[h4 * 4 + 2] = kv.z; kreg[h4 * 4 + 3] = kv.w;
            }
            float dot_a = 0.0f, dot_b = 0.0f, kk2 = 0.0f;
            #pragma unroll
            for (int h = 0; h < 16; ++h) {
                float kv = kreg[h];
                dot_a = fmaf(qa[h], kv, dot_a);
                dot_b = fmaf(qb[h], kv, dot_b);
                kk2 = fmaf(kv, kv, kk2);
            }
            float vreg[16];
            #pragma unroll
            for (int h4 = 0; h4 < 4; ++h4) {
                float4 vv = *(const float4*)&vS[jj][dl][h4 * 4];
                vreg[h4 * 4 + 0] = vv.x; vreg[h4 * 4 + 1] = vv.y;
                vreg[h4 * 4 + 2] = vv.z; vreg[h4 * 4 + 3] = vv.w;
            }
            {   // row b: always active here (j <= i_b)
                float den = q2b + kk2 - 2.0f * dot_b + YAT_EPS;
                float s = dot_b * dot_b / den * inv_scale;
                if (s > mb_) {
                    float c = __expf(mb_ - s);
                    lb *= c;
                    #pragma unroll
                    for (int h = 0; h < 16; ++h) ob[h] *= c;
                    mb_ = s;
                }
                float p = __expf(s - mb_);
                lb += p;
                #pragma unroll
                for (int h = 0; h < 16; ++h) ob[h] = fmaf(p, vreg[h], ob[h]);
            }
            if (j <= i_a) {
                float den = q2a + kk2 - 2.0f * dot_a + YAT_EPS;
                float s = dot_a * dot_a / den * inv_scale;
                if (s > ma) {
                    float c = __expf(ma - s);
                    la *= c;
                    #pragma unroll
                    for (int h = 0; h < 16; ++h) oa[h] *= c;
                    ma = s;
                }
                float p = __expf(s - ma);
                la += p;
                #pragma unroll
                for (int h = 0; h < 16; ++h) oa[h] = fmaf(p, vreg[h], oa[h]);
            }
        }
    }

    const float ila = 1.0f / la;
    const float ilb = 1.0f / lb;
    // attn_out[b][i][d*16 + h]  (reference: out.transpose(0,2,1,3).reshape)
    float* poa = attn_out + (size_t)(b * 1024 + i_a) * 1024 + d * 16;
    float* pob = attn_out + (size_t)(b * 1024 + i_b) * 1024 + d * 16;
    #pragma unroll
    for (int h4 = 0; h4 < 4; ++h4) {
        *(float4*)(poa + h4 * 4) = make_float4(
            oa[h4 * 4 + 0] * ila, oa[h4 * 4 + 1] * ila,
            oa[h4 * 4 + 2] * ila, oa[h4 * 4 + 3] * ila);
        *(float4*)(pob + h4 * 4) = make_float4(
            ob[h4 * 4 + 0] * ilb, ob[h4 * 4 + 1] * ilb,
            ob[h4 * 4 + 2] * ilb, ob[h4 * 4 + 3] * ilb);
    }
}

// ---------------------------------------------------------------------------
extern "C" void kernel_launch(void* const* d_in, const int* in_sizes, int n_in,
                              void* d_out, int out_size, void* d_ws, size_t ws_size,
                              hipStream_t stream)
{
    const float* x          = (const float*)d_in[0];
    // d_in[1] = mask (causal tril, constant) — not needed, causality hard-coded
    const float* w_qkv      = (const float*)d_in[2];
    const float* b_qkv      = (const float*)d_in[3];
    const float* alpha_qkv  = (const float*)d_in[4];
    const float* w_proj     = (const float*)d_in[5];
    const float* b_proj     = (const float*)d_in[6];
    const float* alpha_proj = (const float*)d_in[7];
    const float* alpha_attn = (const float*)d_in[8];
    float* out = (float*)d_out;

    float* ws = (float*)d_ws;
    // Workspace layout (floats): total ~33.6 MB
    float* qkvT = ws;                    // 2*3*64*1024*16 = 6291456
    float* attn = ws + 6291456;          // 2*1024*1024    = 2097152
    float* x2x  = ws + 8388608;          // 2048
    float* x2a  = ws + 8390656;          // 2048
    float* k2q  = ws + 8392704;          // 3072
    float* k2p  = ws + 8395776;          // 1024

    // zero the atomic k2 accumulators (k2q and k2p are contiguous)
    hipMemsetAsync(k2q, 0, (3072 + 1024) * sizeof(float), stream);

    colsumsq_kernel<<<dim3(12, 16), 256, 0, stream>>>(w_qkv, k2q, 1024, 3072);
    colsumsq_kernel<<<dim3(4, 16),  256, 0, stream>>>(w_proj, k2p, 1024, 1024);
    rowsumsq_kernel<<<512, 256, 0, stream>>>(x, x2x, 1024);

    const float sb_qkv = sqrtf(3072.0f) / log1pf(3072.0f);
    gemm_yat_kernel<1><<<dim3(48, 32), 256, 0, stream>>>(
        x, w_qkv, b_qkv, x2x, k2q, alpha_qkv, qkvT, 2048, 3072, 1024, sb_qkv);

    yat_attention_kernel<<<512, 128, 0, stream>>>(qkvT, alpha_attn, attn);

    rowsumsq_kernel<<<512, 256, 0, stream>>>(attn, x2a, 1024);

    const float sb_proj = sqrtf(1024.0f) / log1pf(1024.0f);
    gemm_yat_kernel<0><<<dim3(16, 32), 256, 0, stream>>>(
        attn, w_proj, b_proj, x2a, k2p, alpha_proj, out, 2048, 1024, 1024, sb_proj);
}

// Round 2
// 614.877 us; speedup vs baseline: 1.5818x; 1.5818x over previous
//
#include <hip/hip_runtime.h>
#include <math.h>

#define YAT_EPS (1.0f / 137.0f)

// Logical sizes (fixed): B=2, T=1024, C=1024.
// Attention (faithful to reference transpose): 64 "heads" (d axis),
// per-head dim 16 (h axis), causal, T=1024.

__device__ __forceinline__ float fast_rcp(float x) {
#if __has_builtin(__builtin_amdgcn_rcpf)
    return __builtin_amdgcn_rcpf(x);   // v_rcp_f32, ~1e-7 rel err
#else
    return 1.0f / x;
#endif
}

// ---------------------------------------------------------------------------
// k2[f] = sum_c W[c][f]^2  (column sums of squares), split over K with atomics
// ---------------------------------------------------------------------------
__global__ __launch_bounds__(256) void colsumsq_kernel(
    const float* __restrict__ W, float* __restrict__ k2, int K, int N)
{
    int f = blockIdx.x * 256 + threadIdx.x;
    int chunk = K / gridDim.y;
    int c0 = blockIdx.y * chunk;
    float s = 0.0f;
    for (int c = c0; c < c0 + chunk; ++c) {
        float w = W[(size_t)c * N + f];
        s = fmaf(w, w, s);
    }
    atomicAdd(&k2[f], s);
}

// ---------------------------------------------------------------------------
// out[row] = sum_k X[row][k]^2 ; one wave per row, ncols % 256 == 0
// ---------------------------------------------------------------------------
__global__ __launch_bounds__(256) void rowsumsq_kernel(
    const float* __restrict__ X, float* __restrict__ out, int ncols)
{
    int wave = threadIdx.x >> 6;
    int lane = threadIdx.x & 63;
    int row = blockIdx.x * 4 + wave;
    const float* p = X + (size_t)row * ncols;
    float s = 0.0f;
    for (int k = lane * 4; k < ncols; k += 256) {
        float4 v = *(const float4*)(p + k);
        s = fmaf(v.x, v.x, s);
        s = fmaf(v.y, v.y, s);
        s = fmaf(v.z, v.z, s);
        s = fmaf(v.w, v.w, s);
    }
    #pragma unroll
    for (int off = 32; off > 0; off >>= 1) s += __shfl_down(s, off, 64);
    if (lane == 0) out[row] = s;
}

// ---------------------------------------------------------------------------
// k2k[b][d][t] = sum_h K[b][d][t][h]^2 over the K planes of qkvT (s=1).
// One thread per (b,d,t) row of 16.  131072 rows.
// ---------------------------------------------------------------------------
__global__ __launch_bounds__(256) void sumsq16_kernel(
    const float* __restrict__ qkvT, float* __restrict__ k2k)
{
    int row = blockIdx.x * 256 + threadIdx.x;   // 0..131071
    int b = row >> 16;
    int dt = row & 65535;                        // d*1024 + t
    int d = dt >> 10;
    const float* src = qkvT + ((size_t)((b * 3 + 1) * 64 + d)) * 16384
                            + (size_t)(dt & 1023) * 16;
    float s = 0.0f;
    #pragma unroll
    for (int h4 = 0; h4 < 4; ++h4) {
        float4 v = *(const float4*)(src + h4 * 4);
        s = fmaf(v.x, v.x, s);
        s = fmaf(v.y, v.y, s);
        s = fmaf(v.z, v.z, s);
        s = fmaf(v.w, v.w, s);
    }
    k2k[row] = s;
}

// ---------------------------------------------------------------------------
// Fused YAT dense: out = (A.W)^2 / (x2 + k2 - 2 A.W + eps) * scale + bias
// 64x64 tile, BK=16, 256 threads, 4x4 per thread, fp32.
// MODE 0: standard row-major store.
// MODE 1: scatter into qkvT[b][s][d][t][h] (h contiguous).
// ---------------------------------------------------------------------------
template <int MODE>
__global__ __launch_bounds__(256) void gemm_yat_kernel(
    const float* __restrict__ A, const float* __restrict__ W,
    const float* __restrict__ bias, const float* __restrict__ x2,
    const float* __restrict__ k2, const float* __restrict__ alphap,
    float* __restrict__ out, int M, int N, int K, float scale_base)
{
    __shared__ float As[16][68];
    __shared__ float Bs[16][64];

    const int tid = threadIdx.x;
    const int tx = tid & 15, ty = tid >> 4;
    const int m0 = blockIdx.y * 64, n0 = blockIdx.x * 64;

    const int arow = tid >> 2, ac4 = (tid & 3) * 4;
    const int brow = tid >> 4, bc4 = (tid & 15) * 4;
    const float* Ap = A + (size_t)(m0 + arow) * K + ac4;
    const float* Wp = W + (size_t)brow * N + n0 + bc4;

    float acc[4][4];
    #pragma unroll
    for (int e = 0; e < 4; ++e)
        #pragma unroll
        for (int j = 0; j < 4; ++j) acc[e][j] = 0.0f;

    for (int k0 = 0; k0 < K; k0 += 16) {
        float4 av = *(const float4*)(Ap + k0);
        float4 bv = *(const float4*)(Wp + (size_t)k0 * N);
        __syncthreads();
        As[ac4 + 0][arow] = av.x;
        As[ac4 + 1][arow] = av.y;
        As[ac4 + 2][arow] = av.z;
        As[ac4 + 3][arow] = av.w;
        *(float4*)&Bs[brow][bc4] = bv;
        __syncthreads();
        #pragma unroll
        for (int kk = 0; kk < 16; ++kk) {
            float4 a = *(const float4*)&As[kk][ty * 4];
            float4 b = *(const float4*)&Bs[kk][tx * 4];
            float ar[4] = {a.x, a.y, a.z, a.w};
            float br[4] = {b.x, b.y, b.z, b.w};
            #pragma unroll
            for (int e = 0; e < 4; ++e)
                #pragma unroll
                for (int j = 0; j < 4; ++j)
                    acc[e][j] = fmaf(ar[e], br[j], acc[e][j]);
        }
    }

    const float scale = powf(scale_base, alphap[0]);
    #pragma unroll
    for (int e = 0; e < 4; ++e) {
        const int m = m0 + ty * 4 + e;
        const float xx = x2[m];
        float r[4];
        #pragma unroll
        for (int j = 0; j < 4; ++j) {
            const int n = n0 + tx * 4 + j;
            const float y = acc[e][j];
            const float den = xx + k2[n] - 2.0f * y + YAT_EPS;
            r[j] = y * y / den * scale + bias[n];
        }
        if (MODE == 0) {
            *(float4*)&out[(size_t)m * N + n0 + tx * 4] =
                make_float4(r[0], r[1], r[2], r[3]);
        } else {
            const int b = m >> 10, t = m & 1023;
            #pragma unroll
            for (int j = 0; j < 4; ++j) {
                const int f = n0 + tx * 4 + j;
                const int s = f >> 10, hh = (f >> 6) & 15, d = f & 63;
                out[((size_t)(((b * 3 + s) * 64 + d) * 1024 + t)) * 16 + hh] = r[j];
            }
        }
    }
}

// ---------------------------------------------------------------------------
// Attention v2: wave = 64 lanes <-> 64 q-rows (one per lane) of one (b,d)
// slice; each lane owns TWO rows, from paired i-tiles (tau, 15-tau) so every
// wave does identical work (17 tile-units).  K/V tile (64 j) staged in LDS;
// per-j reads are wave-uniform (pure broadcast, no bank conflicts).  Online
// softmax with +24 headroom so the rescale branch almost never fires.
// Block = 128 threads = 2 waves (2 consecutive d).  Grid = 8 x 32 x 2.
// ---------------------------------------------------------------------------
template <bool WITHA>
__device__ __forceinline__ void yat_tile(
    const float* __restrict__ kT, const float* __restrict__ vT,
    const float* __restrict__ k2T, int j0, int iA, int iB,
    const float (&qa)[16], const float (&qb)[16],
    float q2ea, float q2eb, float inv_scale,
    float& mA, float& lA, float (&oa)[16],
    float& mB, float& lB, float (&ob)[16])
{
    #pragma unroll 2
    for (int jj = 0; jj < 64; ++jj) {
        const int j = j0 + jj;
        const float* kp = kT + jj * 16;
        const float* vp = vT + jj * 16;
        float kr[16], vr[16];
        #pragma unroll
        for (int h4 = 0; h4 < 4; ++h4) {
            float4 kv = *(const float4*)(kp + h4 * 4);
            float4 vv = *(const float4*)(vp + h4 * 4);
            kr[h4*4+0] = kv.x; kr[h4*4+1] = kv.y;
            kr[h4*4+2] = kv.z; kr[h4*4+3] = kv.w;
            vr[h4*4+0] = vv.x; vr[h4*4+1] = vv.y;
            vr[h4*4+2] = vv.z; vr[h4*4+3] = vv.w;
        }
        const float kk2 = k2T[jj];

        float dotB = 0.0f;
        #pragma unroll
        for (int h = 0; h < 16; ++h) dotB = fmaf(qb[h], kr[h], dotB);
        float dotA = 0.0f;
        if (WITHA) {
            #pragma unroll
            for (int h = 0; h < 16; ++h) dotA = fmaf(qa[h], kr[h], dotA);
        }

        {   // row B
            const float den = q2eb + kk2 - 2.0f * dotB;
            float s = dotB * dotB * fast_rcp(den) * inv_scale;
            const bool ok = (j <= iB);
            s = ok ? s : 0.0f;
            if (s > mB) {
                const float mn = s + 24.0f;
                const float c = __expf(mB - mn);
                mB = mn; lB *= c;
                #pragma unroll
                for (int h = 0; h < 16; ++h) ob[h] *= c;
            }
            float p = __expf(s - mB);
            p = ok ? p : 0.0f;
            lB += p;
            #pragma unroll
            for (int h = 0; h < 16; ++h) ob[h] = fmaf(p, vr[h], ob[h]);
        }
        if (WITHA) {  // row A
            const float den = q2ea + kk2 - 2.0f * dotA;
            float s = dotA * dotA * fast_rcp(den) * inv_scale;
            const bool ok = (j <= iA);
            s = ok ? s : 0.0f;
            if (s > mA) {
                const float mn = s + 24.0f;
                const float c = __expf(mA - mn);
                mA = mn; lA *= c;
                #pragma unroll
                for (int h = 0; h < 16; ++h) oa[h] *= c;
            }
            float p = __expf(s - mA);
            p = ok ? p : 0.0f;
            lA += p;
            #pragma unroll
            for (int h = 0; h < 16; ++h) oa[h] = fmaf(p, vr[h], oa[h]);
        }
    }
}

__global__ __launch_bounds__(128) void yat_attention2_kernel(
    const float* __restrict__ qkvT, const float* __restrict__ k2k,
    const float* __restrict__ alphap, float* __restrict__ attn_out)
{
    __shared__ __align__(16) float kS[2][64][16];
    __shared__ __align__(16) float vS[2][64][16];
    __shared__ float k2S[2][64];

    const int tid  = threadIdx.x;
    const int lane = tid & 63;
    const int dsel = tid >> 6;
    const int tau  = blockIdx.x;        // 0..7 -> i-tile pair (tau, 15-tau)
    const int d0   = blockIdx.y * 2;
    const int b    = blockIdx.z;
    const int d    = d0 + dsel;

    const int iA = tau * 64 + lane;
    const int iB = (15 - tau) * 64 + lane;
    const int ntiles = 16 - tau;        // scan j-tiles 0 .. 15-tau

    const float inv_scale = powf(64.0f / log1pf(64.0f), alphap[0]);

    const size_t plane = 16384;
    const float* qpl   = qkvT + (size_t)((b * 3 + 0) * 64 + d) * plane;
    const float* kbase = qkvT + (size_t)((b * 3 + 1) * 64 + d0) * plane;
    const float* vbase = qkvT + (size_t)((b * 3 + 2) * 64 + d0) * plane;
    const float* k2row = k2k + ((size_t)b << 16) + ((size_t)d0 << 10);

    float qa[16], qb[16];
    {
        const float* pa = qpl + (size_t)iA * 16;
        const float* pb = qpl + (size_t)iB * 16;
        #pragma unroll
        for (int h4 = 0; h4 < 4; ++h4) {
            float4 va = *(const float4*)(pa + h4 * 4);
            float4 vb = *(const float4*)(pb + h4 * 4);
            qa[h4*4+0] = va.x; qa[h4*4+1] = va.y;
            qa[h4*4+2] = va.z; qa[h4*4+3] = va.w;
            qb[h4*4+0] = vb.x; qb[h4*4+1] = vb.y;
            qb[h4*4+2] = vb.z; qb[h4*4+3] = vb.w;
        }
    }
    float q2ea = YAT_EPS, q2eb = YAT_EPS;
    #pragma unroll
    for (int h = 0; h < 16; ++h) {
        q2ea = fmaf(qa[h], qa[h], q2ea);
        q2eb = fmaf(qb[h], qb[h], q2eb);
    }

    float mA = -1e30f, lA = 0.0f, mB = -1e30f, lB = 0.0f;
    float oa[16], ob[16];
    #pragma unroll
    for (int h = 0; h < 16; ++h) { oa[h] = 0.0f; ob[h] = 0.0f; }

    float* kflat = &kS[0][0][0];
    float* vflat = &vS[0][0][0];

    for (int jt = 0; jt < ntiles; ++jt) {
        const int j0 = jt * 64;
        __syncthreads();
        #pragma unroll
        for (int r = 0; r < 4; ++r) {
            const int f4i = r * 128 + tid;          // 0..511
            const int ds_ = f4i >> 8;
            const int rem = f4i & 255;
            const size_t go = (size_t)ds_ * plane + (size_t)j0 * 16 + rem * 4;
            *(float4*)(kflat + f4i * 4) = *(const float4*)(kbase + go);
            *(float4*)(vflat + f4i * 4) = *(const float4*)(vbase + go);
        }
        k2S[dsel][lane] = k2row[((size_t)dsel << 10) + j0 + lane];
        __syncthreads();

        if (jt <= tau)
            yat_tile<true>(&kS[dsel][0][0], &vS[dsel][0][0], &k2S[dsel][0],
                           j0, iA, iB, qa, qb, q2ea, q2eb, inv_scale,
                           mA, lA, oa, mB, lB, ob);
        else
            yat_tile<false>(&kS[dsel][0][0], &vS[dsel][0][0], &k2S[dsel][0],
                            j0, iA, iB, qa, qb, q2ea, q2eb, inv_scale,
                            mA, lA, oa, mB, lB, ob);
    }

    const float ila = 1.0f / lA;
    const float ilb = 1.0f / lB;
    float* pA = attn_out + (size_t)(b * 1024 + iA) * 1024 + d * 16;
    float* pB = attn_out + (size_t)(b * 1024 + iB) * 1024 + d * 16;
    #pragma unroll
    for (int h4 = 0; h4 < 4; ++h4) {
        *(float4*)(pA + h4 * 4) = make_float4(
            oa[h4*4+0] * ila, oa[h4*4+1] * ila,
            oa[h4*4+2] * ila, oa[h4*4+3] * ila);
        *(float4*)(pB + h4 * 4) = make_float4(
            ob[h4*4+0] * ilb, ob[h4*4+1] * ilb,
            ob[h4*4+2] * ilb, ob[h4*4+3] * ilb);
    }
}

// ---------------------------------------------------------------------------
extern "C" void kernel_launch(void* const* d_in, const int* in_sizes, int n_in,
                              void* d_out, int out_size, void* d_ws, size_t ws_size,
                              hipStream_t stream)
{
    const float* x          = (const float*)d_in[0];
    // d_in[1] = causal mask, constant — causality hard-coded
    const float* w_qkv      = (const float*)d_in[2];
    const float* b_qkv      = (const float*)d_in[3];
    const float* alpha_qkv  = (const float*)d_in[4];
    const float* w_proj     = (const float*)d_in[5];
    const float* b_proj     = (const float*)d_in[6];
    const float* alpha_proj = (const float*)d_in[7];
    const float* alpha_attn = (const float*)d_in[8];
    float* out = (float*)d_out;

    float* ws = (float*)d_ws;
    // Workspace layout (floats): ~34.2 MB
    float* qkvT = ws;                    // 6291456
    float* attn = ws + 6291456;          // 2097152
    float* x2x  = ws + 8388608;          // 2048
    float* x2a  = ws + 8390656;          // 2048
    float* k2q  = ws + 8392704;          // 3072
    float* k2p  = ws + 8395776;          // 1024
    float* k2k  = ws + 8396800;          // 131072  (k^2 per (b,d,t))

    hipMemsetAsync(k2q, 0, (3072 + 1024) * sizeof(float), stream);

    colsumsq_kernel<<<dim3(12, 16), 256, 0, stream>>>(w_qkv, k2q, 1024, 3072);
    colsumsq_kernel<<<dim3(4, 16),  256, 0, stream>>>(w_proj, k2p, 1024, 1024);
    rowsumsq_kernel<<<512, 256, 0, stream>>>(x, x2x, 1024);

    const float sb_qkv = sqrtf(3072.0f) / log1pf(3072.0f);
    gemm_yat_kernel<1><<<dim3(48, 32), 256, 0, stream>>>(
        x, w_qkv, b_qkv, x2x, k2q, alpha_qkv, qkvT, 2048, 3072, 1024, sb_qkv);

    sumsq16_kernel<<<512, 256, 0, stream>>>(qkvT, k2k);

    yat_attention2_kernel<<<dim3(8, 32, 2), 128, 0, stream>>>(
        qkvT, k2k, alpha_attn, attn);

    rowsumsq_kernel<<<512, 256, 0, stream>>>(attn, x2a, 1024);

    const float sb_proj = sqrtf(1024.0f) / log1pf(1024.0f);
    gemm_yat_kernel<0><<<dim3(16, 32), 256, 0, stream>>>(
        attn, w_proj, b_proj, x2a, k2p, alpha_proj, out, 2048, 1024, 1024, sb_proj);
}

// Round 3
// 460.619 us; speedup vs baseline: 2.1115x; 1.3349x over previous
//
#include <hip/hip_runtime.h>
#include <math.h>

#define YAT_EPS (1.0f / 137.0f)

// Logical sizes (fixed): B=2, T=1024, C=1024.
// Attention (faithful to reference transpose): 64 "heads" (d axis),
// per-head dim 16 (h axis), causal, T=1024.

typedef __bf16 bf16x8 __attribute__((ext_vector_type(8)));
typedef float floatx4 __attribute__((ext_vector_type(4)));

__device__ __forceinline__ float fast_rcp(float x) {
#if __has_builtin(__builtin_amdgcn_rcpf)
    return __builtin_amdgcn_rcpf(x);
#else
    return 1.0f / x;
#endif
}

__device__ __forceinline__ unsigned short f32_bf16(float f) {
    unsigned u = __builtin_bit_cast(unsigned, f);
    u += 0x7fffu + ((u >> 16) & 1u);      // RNE; inputs are finite/normal
    return (unsigned short)(u >> 16);
}
__device__ __forceinline__ float bf16_f32(unsigned short h) {
    unsigned u = ((unsigned)h) << 16;
    return __builtin_bit_cast(float, u);
}

// ---------------------------------------------------------------------------
// k2[f] = sum_c W[c][f]^2  (fp32, exact on original weights)
// ---------------------------------------------------------------------------
__global__ __launch_bounds__(256) void colsumsq_kernel(
    const float* __restrict__ W, float* __restrict__ k2, int K, int N)
{
    int f = blockIdx.x * 256 + threadIdx.x;
    int chunk = K / gridDim.y;
    int c0 = blockIdx.y * chunk;
    float s = 0.0f;
    for (int c = c0; c < c0 + chunk; ++c) {
        float w = W[(size_t)c * N + f];
        s = fmaf(w, w, s);
    }
    atomicAdd(&k2[f], s);
}

// ---------------------------------------------------------------------------
// out[row] = sum_k X[row][k]^2 ; one wave per row
// ---------------------------------------------------------------------------
__global__ __launch_bounds__(256) void rowsumsq_kernel(
    const float* __restrict__ X, float* __restrict__ out, int ncols)
{
    int wave = threadIdx.x >> 6;
    int lane = threadIdx.x & 63;
    int row = blockIdx.x * 4 + wave;
    const float* p = X + (size_t)row * ncols;
    float s = 0.0f;
    for (int k = lane * 4; k < ncols; k += 256) {
        float4 v = *(const float4*)(p + k);
        s = fmaf(v.x, v.x, s);
        s = fmaf(v.y, v.y, s);
        s = fmaf(v.z, v.z, s);
        s = fmaf(v.w, v.w, s);
    }
    #pragma unroll
    for (int off = 32; off > 0; off >>= 1) s += __shfl_down(s, off, 64);
    if (lane == 0) out[row] = s;
}

// ---------------------------------------------------------------------------
// k2k[b][d][t] = sum_h K[b][d][t][h]^2 over the K planes of qkvT
// ---------------------------------------------------------------------------
__global__ __launch_bounds__(256) void sumsq16_kernel(
    const float* __restrict__ qkvT, float* __restrict__ k2k)
{
    int row = blockIdx.x * 256 + threadIdx.x;   // 0..131071
    int b = row >> 16;
    int dt = row & 65535;
    int d = dt >> 10;
    const float* src = qkvT + ((size_t)((b * 3 + 1) * 64 + d)) * 16384
                            + (size_t)(dt & 1023) * 16;
    float s = 0.0f;
    #pragma unroll
    for (int h4 = 0; h4 < 4; ++h4) {
        float4 v = *(const float4*)(src + h4 * 4);
        s = fmaf(v.x, v.x, s);
        s = fmaf(v.y, v.y, s);
        s = fmaf(v.z, v.z, s);
        s = fmaf(v.w, v.w, s);
    }
    k2k[row] = s;
}

// ---------------------------------------------------------------------------
// fp32 -> bf16 hi/lo split, same layout.  n4 = nelem/4.
// ---------------------------------------------------------------------------
__global__ __launch_bounds__(256) void conv_hl_kernel(
    const float* __restrict__ src, unsigned short* __restrict__ hi,
    unsigned short* __restrict__ lo, int n4)
{
    int i = blockIdx.x * 256 + threadIdx.x;
    if (i >= n4) return;
    float4 v = *(const float4*)(src + (size_t)i * 4);
    float vv[4] = {v.x, v.y, v.z, v.w};
    unsigned short hh[4], ll[4];
    #pragma unroll
    for (int e = 0; e < 4; ++e) {
        hh[e] = f32_bf16(vv[e]);
        ll[e] = f32_bf16(vv[e] - bf16_f32(hh[e]));
    }
    *(ushort4*)(hi + (size_t)i * 4) = make_ushort4(hh[0], hh[1], hh[2], hh[3]);
    *(ushort4*)(lo + (size_t)i * 4) = make_ushort4(ll[0], ll[1], ll[2], ll[3]);
}

// ---------------------------------------------------------------------------
// W[K][N] fp32 -> Wt_hi/Wt_lo [N][K] bf16 (transposed, k-contiguous)
// block (32,8), grid (N/32, K/32)
// ---------------------------------------------------------------------------
__global__ void convtrans_kernel(
    const float* __restrict__ W, unsigned short* __restrict__ th,
    unsigned short* __restrict__ tl, int K, int N)
{
    __shared__ float t[32][33];
    int tx = threadIdx.x, ty = threadIdx.y;
    int n0 = blockIdx.x * 32, k0 = blockIdx.y * 32;
    #pragma unroll
    for (int r = 0; r < 4; ++r)
        t[ty + r * 8][tx] = W[(size_t)(k0 + ty + r * 8) * N + n0 + tx];
    __syncthreads();
    #pragma unroll
    for (int r = 0; r < 4; ++r) {
        int nl = ty + r * 8;
        float v = t[tx][nl];
        unsigned short h = f32_bf16(v);
        th[(size_t)(n0 + nl) * K + k0 + tx] = h;
        tl[(size_t)(n0 + nl) * K + k0 + tx] = f32_bf16(v - bf16_f32(h));
    }
}

// ---------------------------------------------------------------------------
// Split-bf16 MFMA YAT-dense GEMM.
// Y = A.B (fp32 via hi*hi + hi*lo + lo*hi), then
// out = Y^2/(x2 + k2 - 2Y + eps)*scale + bias.
// A (hi/lo): [M][K] bf16.  B (hi/lo): [N][K] bf16 (pre-transposed).
// Tile 64(m) x 128(n), BK=32, 256 threads = 4 waves, each wave 2x4 C-tiles
// of 16x16 via v_mfma_f32_16x16x32_bf16.
// MODE 0: row-major store.  MODE 1: scatter to qkvT[b][s][d][t][h].
// ---------------------------------------------------------------------------
template <int MODE>
__global__ __launch_bounds__(256) void gemm_yat_mfma_kernel(
    const unsigned short* __restrict__ Ah, const unsigned short* __restrict__ Al,
    const unsigned short* __restrict__ Bh, const unsigned short* __restrict__ Bl,
    const float* __restrict__ bias, const float* __restrict__ x2,
    const float* __restrict__ k2, const float* __restrict__ alphap,
    float* __restrict__ out, int N, int K, float scale_base)
{
    // staging: [Ah 4KB | Al 4KB | Bh 8KB | Bl 8KB] = 24 KB, packed (no pad:
    // global_load_lds lands lane i at base + i*16)
    __shared__ __align__(16) unsigned short sbuf[12288];

    const int tid = threadIdx.x;
    const int w = tid >> 6, l = tid & 63;
    const int lane16 = l & 15, quad = l >> 4;
    const int wm = w & 1, wn = w >> 1;
    const int m0 = blockIdx.y * 64, n0 = blockIdx.x * 128;

    floatx4 acc[2][4];
    #pragma unroll
    for (int tm = 0; tm < 2; ++tm)
        #pragma unroll
        for (int tn = 0; tn < 4; ++tn)
            acc[tm][tn] = (floatx4){0.f, 0.f, 0.f, 0.f};

    for (int k0 = 0; k0 < K; k0 += 32) {
        __syncthreads();
        #pragma unroll
        for (int i = 0; i < 6; ++i) {
            const int o = (i * 4 + w) * 1024;   // byte offset in sbuf (uniform/wave)
            const unsigned short* gp;
            if (o < 8192) {                      // A region
                const unsigned short* g = (o < 4096) ? Ah : Al;
                const int oo = o & 4095;
                gp = g + (size_t)(m0 + (oo >> 6) + (l >> 2)) * K + k0 + (l & 3) * 8;
            } else {                             // B region
                const int ob = o - 8192;
                const unsigned short* g = (ob < 8192) ? Bh : Bl;
                const int oo = ob & 8191;
                gp = g + (size_t)(n0 + (oo >> 6) + (l >> 2)) * K + k0 + (l & 3) * 8;
            }
            __builtin_amdgcn_global_load_lds(
                (const __attribute__((address_space(1))) unsigned int*)gp,
                (__attribute__((address_space(3))) unsigned int*)((char*)sbuf + o),
                16, 0, 0);
        }
        __syncthreads();

        bf16x8 afh[2], afl[2], bfh[4], bfl[4];
        #pragma unroll
        for (int tm = 0; tm < 2; ++tm) {
            const int base = (wm * 32 + tm * 16 + lane16) * 32 + quad * 8;
            afh[tm] = *(const bf16x8*)(sbuf + base);
            afl[tm] = *(const bf16x8*)(sbuf + 2048 + base);
        }
        #pragma unroll
        for (int tn = 0; tn < 4; ++tn) {
            const int nb = (wn * 64 + tn * 16 + lane16) * 32 + quad * 8;
            bfh[tn] = *(const bf16x8*)(sbuf + 4096 + nb);
            bfl[tn] = *(const bf16x8*)(sbuf + 8192 + nb);
        }
        #pragma unroll
        for (int tm = 0; tm < 2; ++tm)
            #pragma unroll
            for (int tn = 0; tn < 4; ++tn) {
                acc[tm][tn] = __builtin_amdgcn_mfma_f32_16x16x32_bf16(
                    afh[tm], bfh[tn], acc[tm][tn], 0, 0, 0);
                acc[tm][tn] = __builtin_amdgcn_mfma_f32_16x16x32_bf16(
                    afh[tm], bfl[tn], acc[tm][tn], 0, 0, 0);
                acc[tm][tn] = __builtin_amdgcn_mfma_f32_16x16x32_bf16(
                    afl[tm], bfh[tn], acc[tm][tn], 0, 0, 0);
            }
    }

    const float scale = powf(scale_base, alphap[0]);
    #pragma unroll
    for (int tm = 0; tm < 2; ++tm) {
        #pragma unroll
        for (int tn = 0; tn < 4; ++tn) {
            const int n = n0 + wn * 64 + tn * 16 + lane16;
            const float kk = k2[n];
            const float bb = bias[n];
            #pragma unroll
            for (int r = 0; r < 4; ++r) {
                const int m = m0 + wm * 32 + tm * 16 + quad * 4 + r;
                const float y = acc[tm][tn][r];
                const float den = x2[m] + kk - 2.0f * y + YAT_EPS;
                const float val = y * y / den * scale + bb;
                if (MODE == 0) {
                    out[(size_t)m * N + n] = val;
                } else {
                    const int b = m >> 10, t = m & 1023;
                    const int s = n >> 10, hh = (n >> 6) & 15, d = n & 63;
                    out[((size_t)(((b * 3 + s) * 64 + d) * 1024 + t)) * 16 + hh] = val;
                }
            }
        }
    }
}

// ---------------------------------------------------------------------------
// Attention: wave = 64 q-rows of one (b,d) slice, 2 rows/lane from paired
// i-tiles (tau, 15-tau) for uniform work.  Epilogue writes bf16 hi/lo rows
// (for the split-bf16 proj GEMM) and atomically accumulates x2a.
// ---------------------------------------------------------------------------
template <bool WITHA>
__device__ __forceinline__ void yat_tile(
    const float* __restrict__ kT, const float* __restrict__ vT,
    const float* __restrict__ k2T, int j0, int iA, int iB,
    const float (&qa)[16], const float (&qb)[16],
    float q2ea, float q2eb, float inv_scale,
    float& mA, float& lA, float (&oa)[16],
    float& mB, float& lB, float (&ob)[16])
{
    #pragma unroll 2
    for (int jj = 0; jj < 64; ++jj) {
        const int j = j0 + jj;
        const float* kp = kT + jj * 16;
        const float* vp = vT + jj * 16;
        float kr[16], vr[16];
        #pragma unroll
        for (int h4 = 0; h4 < 4; ++h4) {
            float4 kv = *(const float4*)(kp + h4 * 4);
            float4 vv = *(const float4*)(vp + h4 * 4);
            kr[h4*4+0] = kv.x; kr[h4*4+1] = kv.y;
            kr[h4*4+2] = kv.z; kr[h4*4+3] = kv.w;
            vr[h4*4+0] = vv.x; vr[h4*4+1] = vv.y;
            vr[h4*4+2] = vv.z; vr[h4*4+3] = vv.w;
        }
        const float kk2 = k2T[jj];

        float dotB = 0.0f;
        #pragma unroll
        for (int h = 0; h < 16; ++h) dotB = fmaf(qb[h], kr[h], dotB);
        float dotA = 0.0f;
        if (WITHA) {
            #pragma unroll
            for (int h = 0; h < 16; ++h) dotA = fmaf(qa[h], kr[h], dotA);
        }

        {   // row B
            const float den = q2eb + kk2 - 2.0f * dotB;
            float s = dotB * dotB * fast_rcp(den) * inv_scale;
            const bool ok = (j <= iB);
            s = ok ? s : 0.0f;
            if (s > mB) {
                const float mn = s + 24.0f;
                const float c = __expf(mB - mn);
                mB = mn; lB *= c;
                #pragma unroll
                for (int h = 0; h < 16; ++h) ob[h] *= c;
            }
            float p = __expf(s - mB);
            p = ok ? p : 0.0f;
            lB += p;
            #pragma unroll
            for (int h = 0; h < 16; ++h) ob[h] = fmaf(p, vr[h], ob[h]);
        }
        if (WITHA) {
            const float den = q2ea + kk2 - 2.0f * dotA;
            float s = dotA * dotA * fast_rcp(den) * inv_scale;
            const bool ok = (j <= iA);
            s = ok ? s : 0.0f;
            if (s > mA) {
                const float mn = s + 24.0f;
                const float c = __expf(mA - mn);
                mA = mn; lA *= c;
                #pragma unroll
                for (int h = 0; h < 16; ++h) oa[h] *= c;
            }
            float p = __expf(s - mA);
            p = ok ? p : 0.0f;
            lA += p;
            #pragma unroll
            for (int h = 0; h < 16; ++h) oa[h] = fmaf(p, vr[h], oa[h]);
        }
    }
}

__device__ __forceinline__ void write_row_hl(
    unsigned short* __restrict__ ah, unsigned short* __restrict__ al,
    float* __restrict__ x2a, int rowidx, size_t off,
    const float (&o)[16], float il)
{
    unsigned short hb[16], lb16[16];
    float s2 = 0.0f;
    #pragma unroll
    for (int h = 0; h < 16; ++h) {
        float v = o[h] * il;
        unsigned short hh = f32_bf16(v);
        hb[h] = hh;
        lb16[h] = f32_bf16(v - bf16_f32(hh));
        s2 = fmaf(v, v, s2);
    }
    #pragma unroll
    for (int q = 0; q < 4; ++q) {
        *(ushort4*)(ah + off + q * 4) =
            make_ushort4(hb[q*4], hb[q*4+1], hb[q*4+2], hb[q*4+3]);
        *(ushort4*)(al + off + q * 4) =
            make_ushort4(lb16[q*4], lb16[q*4+1], lb16[q*4+2], lb16[q*4+3]);
    }
    atomicAdd(&x2a[rowidx], s2);
}

__global__ __launch_bounds__(128) void yat_attention2_kernel(
    const float* __restrict__ qkvT, const float* __restrict__ k2k,
    const float* __restrict__ alphap,
    unsigned short* __restrict__ attn_h, unsigned short* __restrict__ attn_l,
    float* __restrict__ x2a)
{
    __shared__ __align__(16) float kS[2][64][16];
    __shared__ __align__(16) float vS[2][64][16];
    __shared__ float k2S[2][64];

    const int tid  = threadIdx.x;
    const int lane = tid & 63;
    const int dsel = tid >> 6;
    const int tau  = blockIdx.x;
    const int d0   = blockIdx.y * 2;
    const int b    = blockIdx.z;
    const int d    = d0 + dsel;

    const int iA = tau * 64 + lane;
    const int iB = (15 - tau) * 64 + lane;
    const int ntiles = 16 - tau;

    const float inv_scale = powf(64.0f / log1pf(64.0f), alphap[0]);

    const size_t plane = 16384;
    const float* qpl   = qkvT + (size_t)((b * 3 + 0) * 64 + d) * plane;
    const float* kbase = qkvT + (size_t)((b * 3 + 1) * 64 + d0) * plane;
    const float* vbase = qkvT + (size_t)((b * 3 + 2) * 64 + d0) * plane;
    const float* k2row = k2k + ((size_t)b << 16) + ((size_t)d0 << 10);

    float qa[16], qb[16];
    {
        const float* pa = qpl + (size_t)iA * 16;
        const float* pb = qpl + (size_t)iB * 16;
        #pragma unroll
        for (int h4 = 0; h4 < 4; ++h4) {
            float4 va = *(const float4*)(pa + h4 * 4);
            float4 vb = *(const float4*)(pb + h4 * 4);
            qa[h4*4+0] = va.x; qa[h4*4+1] = va.y;
            qa[h4*4+2] = va.z; qa[h4*4+3] = va.w;
            qb[h4*4+0] = vb.x; qb[h4*4+1] = vb.y;
            qb[h4*4+2] = vb.z; qb[h4*4+3] = vb.w;
        }
    }
    float q2ea = YAT_EPS, q2eb = YAT_EPS;
    #pragma unroll
    for (int h = 0; h < 16; ++h) {
        q2ea = fmaf(qa[h], qa[h], q2ea);
        q2eb = fmaf(qb[h], qb[h], q2eb);
    }

    float mA = -1e30f, lA = 0.0f, mB = -1e30f, lB = 0.0f;
    float oa[16], ob[16];
    #pragma unroll
    for (int h = 0; h < 16; ++h) { oa[h] = 0.0f; ob[h] = 0.0f; }

    float* kflat = &kS[0][0][0];
    float* vflat = &vS[0][0][0];

    for (int jt = 0; jt < ntiles; ++jt) {
        const int j0 = jt * 64;
        __syncthreads();
        #pragma unroll
        for (int r = 0; r < 4; ++r) {
            const int f4i = r * 128 + tid;
            const int ds_ = f4i >> 8;
            const int rem = f4i & 255;
            const size_t go = (size_t)ds_ * plane + (size_t)j0 * 16 + rem * 4;
            *(float4*)(kflat + f4i * 4) = *(const float4*)(kbase + go);
            *(float4*)(vflat + f4i * 4) = *(const float4*)(vbase + go);
        }
        k2S[dsel][lane] = k2row[((size_t)dsel << 10) + j0 + lane];
        __syncthreads();

        if (jt <= tau)
            yat_tile<true>(&kS[dsel][0][0], &vS[dsel][0][0], &k2S[dsel][0],
                           j0, iA, iB, qa, qb, q2ea, q2eb, inv_scale,
                           mA, lA, oa, mB, lB, ob);
        else
            yat_tile<false>(&kS[dsel][0][0], &vS[dsel][0][0], &k2S[dsel][0],
                            j0, iA, iB, qa, qb, q2ea, q2eb, inv_scale,
                            mA, lA, oa, mB, lB, ob);
    }

    const int rowA = b * 1024 + iA;
    const int rowB = b * 1024 + iB;
    write_row_hl(attn_h, attn_l, x2a, rowA,
                 (size_t)rowA * 1024 + d * 16, oa, 1.0f / lA);
    write_row_hl(attn_h, attn_l, x2a, rowB,
                 (size_t)rowB * 1024 + d * 16, ob, 1.0f / lB);
}

// ---------------------------------------------------------------------------
extern "C" void kernel_launch(void* const* d_in, const int* in_sizes, int n_in,
                              void* d_out, int out_size, void* d_ws, size_t ws_size,
                              hipStream_t stream)
{
    const float* x          = (const float*)d_in[0];
    // d_in[1] = causal mask, constant — causality hard-coded
    const float* w_qkv      = (const float*)d_in[2];
    const float* b_qkv      = (const float*)d_in[3];
    const float* alpha_qkv  = (const float*)d_in[4];
    const float* w_proj     = (const float*)d_in[5];
    const float* b_proj     = (const float*)d_in[6];
    const float* alpha_proj = (const float*)d_in[7];
    const float* alpha_attn = (const float*)d_in[8];
    float* out = (float*)d_out;

    float* ws = (float*)d_ws;
    // Workspace (float slots), ~51 MB total:
    float*          qkvT = ws;                                   // 6291456
    unsigned short* WtQh = (unsigned short*)(ws + 6291456);      // 3072x1024 bf16
    unsigned short* WtQl = (unsigned short*)(ws + 7864320);
    unsigned short* WtPh = (unsigned short*)(ws + 9437184);      // 1024x1024 bf16
    unsigned short* WtPl = (unsigned short*)(ws + 9961472);
    unsigned short* xh   = (unsigned short*)(ws + 10485760);     // 2048x1024 bf16
    unsigned short* xl   = (unsigned short*)(ws + 11534336);
    float* x2x  = ws + 12582912;   // 2048
    float* x2a  = ws + 12584960;   // 2048 (atomic)
    float* k2q  = ws + 12587008;   // 3072 (atomic)
    float* k2p  = ws + 12590080;   // 1024 (atomic)
    float* k2k  = ws + 12591104;   // 131072
    // attn hi/lo alias the WtQ region (WtQ dead after the QKV GEMM)
    unsigned short* attn_h = WtQh;
    unsigned short* attn_l = WtQl;

    // zero atomic accumulators: x2a, k2q, k2p are contiguous
    hipMemsetAsync(x2a, 0, (2048 + 3072 + 1024) * sizeof(float), stream);

    // conversions / precomputations
    convtrans_kernel<<<dim3(96, 32), dim3(32, 8), 0, stream>>>(
        w_qkv, WtQh, WtQl, 1024, 3072);
    convtrans_kernel<<<dim3(32, 32), dim3(32, 8), 0, stream>>>(
        w_proj, WtPh, WtPl, 1024, 1024);
    conv_hl_kernel<<<2048, 256, 0, stream>>>(x, xh, xl, 524288);
    colsumsq_kernel<<<dim3(12, 16), 256, 0, stream>>>(w_qkv, k2q, 1024, 3072);
    colsumsq_kernel<<<dim3(4, 16),  256, 0, stream>>>(w_proj, k2p, 1024, 1024);
    rowsumsq_kernel<<<512, 256, 0, stream>>>(x, x2x, 1024);

    // QKV: [2048x1024] . [1024x3072], scatter into qkvT
    const float sb_qkv = sqrtf(3072.0f) / log1pf(3072.0f);
    gemm_yat_mfma_kernel<1><<<dim3(24, 32), 256, 0, stream>>>(
        xh, xl, WtQh, WtQl, b_qkv, x2x, k2q, alpha_qkv, qkvT,
        3072, 1024, sb_qkv);

    sumsq16_kernel<<<512, 256, 0, stream>>>(qkvT, k2k);

    yat_attention2_kernel<<<dim3(8, 32, 2), 128, 0, stream>>>(
        qkvT, k2k, alpha_attn, attn_h, attn_l, x2a);

    // proj: [2048x1024] . [1024x1024] -> out
    const float sb_proj = sqrtf(1024.0f) / log1pf(1024.0f);
    gemm_yat_mfma_kernel<0><<<dim3(8, 32), 256, 0, stream>>>(
        attn_h, attn_l, WtPh, WtPl, b_proj, x2a, k2p, alpha_proj, out,
        1024, 1024, sb_proj);
}

// Round 4
// 374.075 us; speedup vs baseline: 2.6000x; 1.2314x over previous
//
#include <hip/hip_runtime.h>
#include <math.h>

#define YAT_EPS (1.0f / 137.0f)

// Logical sizes (fixed): B=2, T=1024, C=1024.
// Attention (faithful to reference transpose): 64 "heads" (d axis),
// per-head dim 16 (h axis), causal, T=1024.

typedef __bf16 bf16x8 __attribute__((ext_vector_type(8)));
typedef float floatx4 __attribute__((ext_vector_type(4)));

__device__ __forceinline__ float fast_rcp(float x) {
#if __has_builtin(__builtin_amdgcn_rcpf)
    return __builtin_amdgcn_rcpf(x);
#else
    return 1.0f / x;
#endif
}

__device__ __forceinline__ unsigned short f32_bf16(float f) {
    unsigned u = __builtin_bit_cast(unsigned, f);
    u += 0x7fffu + ((u >> 16) & 1u);      // RNE; inputs are finite/normal
    return (unsigned short)(u >> 16);
}
__device__ __forceinline__ float bf16_f32(unsigned short h) {
    unsigned u = ((unsigned)h) << 16;
    return __builtin_bit_cast(float, u);
}

// ---------------------------------------------------------------------------
// k2[f] = sum_c W[c][f]^2  (fp32, exact on original weights)
// ---------------------------------------------------------------------------
__global__ __launch_bounds__(256) void colsumsq_kernel(
    const float* __restrict__ W, float* __restrict__ k2, int K, int N)
{
    int f = blockIdx.x * 256 + threadIdx.x;
    int chunk = K / gridDim.y;
    int c0 = blockIdx.y * chunk;
    float s = 0.0f;
    for (int c = c0; c < c0 + chunk; ++c) {
        float w = W[(size_t)c * N + f];
        s = fmaf(w, w, s);
    }
    atomicAdd(&k2[f], s);
}

// ---------------------------------------------------------------------------
// out[row] = sum_k X[row][k]^2 ; one wave per row
// ---------------------------------------------------------------------------
__global__ __launch_bounds__(256) void rowsumsq_kernel(
    const float* __restrict__ X, float* __restrict__ out, int ncols)
{
    int wave = threadIdx.x >> 6;
    int lane = threadIdx.x & 63;
    int row = blockIdx.x * 4 + wave;
    const float* p = X + (size_t)row * ncols;
    float s = 0.0f;
    for (int k = lane * 4; k < ncols; k += 256) {
        float4 v = *(const float4*)(p + k);
        s = fmaf(v.x, v.x, s);
        s = fmaf(v.y, v.y, s);
        s = fmaf(v.z, v.z, s);
        s = fmaf(v.w, v.w, s);
    }
    #pragma unroll
    for (int off = 32; off > 0; off >>= 1) s += __shfl_down(s, off, 64);
    if (lane == 0) out[row] = s;
}

// ---------------------------------------------------------------------------
// k2k[b][d][t] = sum_h K[b][d][t][h]^2 over the K planes of qkvT
// ---------------------------------------------------------------------------
__global__ __launch_bounds__(256) void sumsq16_kernel(
    const float* __restrict__ qkvT, float* __restrict__ k2k)
{
    int row = blockIdx.x * 256 + threadIdx.x;   // 0..131071
    int b = row >> 16;
    int dt = row & 65535;
    int d = dt >> 10;
    const float* src = qkvT + ((size_t)((b * 3 + 1) * 64 + d)) * 16384
                            + (size_t)(dt & 1023) * 16;
    float s = 0.0f;
    #pragma unroll
    for (int h4 = 0; h4 < 4; ++h4) {
        float4 v = *(const float4*)(src + h4 * 4);
        s = fmaf(v.x, v.x, s);
        s = fmaf(v.y, v.y, s);
        s = fmaf(v.z, v.z, s);
        s = fmaf(v.w, v.w, s);
    }
    k2k[row] = s;
}

// ---------------------------------------------------------------------------
// fp32 -> bf16 hi/lo split, same layout.  n4 = nelem/4.
// ---------------------------------------------------------------------------
__global__ __launch_bounds__(256) void conv_hl_kernel(
    const float* __restrict__ src, unsigned short* __restrict__ hi,
    unsigned short* __restrict__ lo, int n4)
{
    int i = blockIdx.x * 256 + threadIdx.x;
    if (i >= n4) return;
    float4 v = *(const float4*)(src + (size_t)i * 4);
    float vv[4] = {v.x, v.y, v.z, v.w};
    unsigned short hh[4], ll[4];
    #pragma unroll
    for (int e = 0; e < 4; ++e) {
        hh[e] = f32_bf16(vv[e]);
        ll[e] = f32_bf16(vv[e] - bf16_f32(hh[e]));
    }
    *(ushort4*)(hi + (size_t)i * 4) = make_ushort4(hh[0], hh[1], hh[2], hh[3]);
    *(ushort4*)(lo + (size_t)i * 4) = make_ushort4(ll[0], ll[1], ll[2], ll[3]);
}

// ---------------------------------------------------------------------------
// W[K][N] fp32 -> Wt_hi/Wt_lo [N][K] bf16 (transposed, k-contiguous)
// ---------------------------------------------------------------------------
__global__ void convtrans_kernel(
    const float* __restrict__ W, unsigned short* __restrict__ th,
    unsigned short* __restrict__ tl, int K, int N)
{
    __shared__ float t[32][33];
    int tx = threadIdx.x, ty = threadIdx.y;
    int n0 = blockIdx.x * 32, k0 = blockIdx.y * 32;
    #pragma unroll
    for (int r = 0; r < 4; ++r)
        t[ty + r * 8][tx] = W[(size_t)(k0 + ty + r * 8) * N + n0 + tx];
    __syncthreads();
    #pragma unroll
    for (int r = 0; r < 4; ++r) {
        int nl = ty + r * 8;
        float v = t[tx][nl];
        unsigned short h = f32_bf16(v);
        th[(size_t)(n0 + nl) * K + k0 + tx] = h;
        tl[(size_t)(n0 + nl) * K + k0 + tx] = f32_bf16(v - bf16_f32(h));
    }
}

// ---------------------------------------------------------------------------
// Split-bf16 MFMA YAT-dense GEMM (unchanged from round 3).
// ---------------------------------------------------------------------------
template <int MODE>
__global__ __launch_bounds__(256) void gemm_yat_mfma_kernel(
    const unsigned short* __restrict__ Ah, const unsigned short* __restrict__ Al,
    const unsigned short* __restrict__ Bh, const unsigned short* __restrict__ Bl,
    const float* __restrict__ bias, const float* __restrict__ x2,
    const float* __restrict__ k2, const float* __restrict__ alphap,
    float* __restrict__ out, int N, int K, float scale_base)
{
    __shared__ __align__(16) unsigned short sbuf[12288];

    const int tid = threadIdx.x;
    const int w = tid >> 6, l = tid & 63;
    const int lane16 = l & 15, quad = l >> 4;
    const int wm = w & 1, wn = w >> 1;
    const int m0 = blockIdx.y * 64, n0 = blockIdx.x * 128;

    floatx4 acc[2][4];
    #pragma unroll
    for (int tm = 0; tm < 2; ++tm)
        #pragma unroll
        for (int tn = 0; tn < 4; ++tn)
            acc[tm][tn] = (floatx4){0.f, 0.f, 0.f, 0.f};

    for (int k0 = 0; k0 < K; k0 += 32) {
        __syncthreads();
        #pragma unroll
        for (int i = 0; i < 6; ++i) {
            const int o = (i * 4 + w) * 1024;
            const unsigned short* gp;
            if (o < 8192) {
                const unsigned short* g = (o < 4096) ? Ah : Al;
                const int oo = o & 4095;
                gp = g + (size_t)(m0 + (oo >> 6) + (l >> 2)) * K + k0 + (l & 3) * 8;
            } else {
                const int ob = o - 8192;
                const unsigned short* g = (ob < 8192) ? Bh : Bl;
                const int oo = ob & 8191;
                gp = g + (size_t)(n0 + (oo >> 6) + (l >> 2)) * K + k0 + (l & 3) * 8;
            }
            __builtin_amdgcn_global_load_lds(
                (const __attribute__((address_space(1))) unsigned int*)gp,
                (__attribute__((address_space(3))) unsigned int*)((char*)sbuf + o),
                16, 0, 0);
        }
        __syncthreads();

        bf16x8 afh[2], afl[2], bfh[4], bfl[4];
        #pragma unroll
        for (int tm = 0; tm < 2; ++tm) {
            const int base = (wm * 32 + tm * 16 + lane16) * 32 + quad * 8;
            afh[tm] = *(const bf16x8*)(sbuf + base);
            afl[tm] = *(const bf16x8*)(sbuf + 2048 + base);
        }
        #pragma unroll
        for (int tn = 0; tn < 4; ++tn) {
            const int nb = (wn * 64 + tn * 16 + lane16) * 32 + quad * 8;
            bfh[tn] = *(const bf16x8*)(sbuf + 4096 + nb);
            bfl[tn] = *(const bf16x8*)(sbuf + 8192 + nb);
        }
        #pragma unroll
        for (int tm = 0; tm < 2; ++tm)
            #pragma unroll
            for (int tn = 0; tn < 4; ++tn) {
                acc[tm][tn] = __builtin_amdgcn_mfma_f32_16x16x32_bf16(
                    afh[tm], bfh[tn], acc[tm][tn], 0, 0, 0);
                acc[tm][tn] = __builtin_amdgcn_mfma_f32_16x16x32_bf16(
                    afh[tm], bfl[tn], acc[tm][tn], 0, 0, 0);
                acc[tm][tn] = __builtin_amdgcn_mfma_f32_16x16x32_bf16(
                    afl[tm], bfh[tn], acc[tm][tn], 0, 0, 0);
            }
    }

    const float scale = powf(scale_base, alphap[0]);
    #pragma unroll
    for (int tm = 0; tm < 2; ++tm) {
        #pragma unroll
        for (int tn = 0; tn < 4; ++tn) {
            const int n = n0 + wn * 64 + tn * 16 + lane16;
            const float kk = k2[n];
            const float bb = bias[n];
            #pragma unroll
            for (int r = 0; r < 4; ++r) {
                const int m = m0 + wm * 32 + tm * 16 + quad * 4 + r;
                const float y = acc[tm][tn][r];
                const float den = x2[m] + kk - 2.0f * y + YAT_EPS;
                const float val = y * y / den * scale + bb;
                if (MODE == 0) {
                    out[(size_t)m * N + n] = val;
                } else {
                    const int b = m >> 10, t = m & 1023;
                    const int s = n >> 10, hh = (n >> 6) & 15, d = n & 63;
                    out[((size_t)(((b * 3 + s) * 64 + d) * 1024 + t)) * 16 + hh] = val;
                }
            }
        }
    }
}

// ---------------------------------------------------------------------------
// Attention v3: j-split flash-decoding.
// Block = 256 threads = 4 waves: (dsel = wid&1, half = wid>>1).
// Wave = 64 lanes <-> 64 q-rows; 2 rows/lane from paired i-tiles (tau,15-tau).
// Half h processes j-tiles jt with jt%2==h (alternating -> balanced).
// Each (dsel,half) has its own LDS K/V tile; final LDS merge of the two
// halves' (m,l,o) online-softmax states; half0 writes output.
// ---------------------------------------------------------------------------
template <bool WITHA>
__device__ __forceinline__ void yat_tile(
    const float* __restrict__ kT, const float* __restrict__ vT,
    const float* __restrict__ k2T, int j0, int iA, int iB,
    const float (&qa)[16], const float (&qb)[16],
    float q2ea, float q2eb, float inv_scale,
    float& mA, float& lA, float (&oa)[16],
    float& mB, float& lB, float (&ob)[16])
{
    #pragma unroll 2
    for (int jj = 0; jj < 64; ++jj) {
        const int j = j0 + jj;
        const float* kp = kT + jj * 16;
        const float* vp = vT + jj * 16;
        float kr[16], vr[16];
        #pragma unroll
        for (int h4 = 0; h4 < 4; ++h4) {
            float4 kv = *(const float4*)(kp + h4 * 4);
            float4 vv = *(const float4*)(vp + h4 * 4);
            kr[h4*4+0] = kv.x; kr[h4*4+1] = kv.y;
            kr[h4*4+2] = kv.z; kr[h4*4+3] = kv.w;
            vr[h4*4+0] = vv.x; vr[h4*4+1] = vv.y;
            vr[h4*4+2] = vv.z; vr[h4*4+3] = vv.w;
        }
        const float kk2 = k2T[jj];

        float dotB = 0.0f;
        #pragma unroll
        for (int h = 0; h < 16; ++h) dotB = fmaf(qb[h], kr[h], dotB);
        float dotA = 0.0f;
        if (WITHA) {
            #pragma unroll
            for (int h = 0; h < 16; ++h) dotA = fmaf(qa[h], kr[h], dotA);
        }

        {   // row B
            const float den = q2eb + kk2 - 2.0f * dotB;
            float s = dotB * dotB * fast_rcp(den) * inv_scale;
            const bool ok = (j <= iB);
            s = ok ? s : 0.0f;
            if (s > mB) {
                const float mn = s + 24.0f;
                const float c = __expf(mB - mn);
                mB = mn; lB *= c;
                #pragma unroll
                for (int h = 0; h < 16; ++h) ob[h] *= c;
            }
            float p = __expf(s - mB);
            p = ok ? p : 0.0f;
            lB += p;
            #pragma unroll
            for (int h = 0; h < 16; ++h) ob[h] = fmaf(p, vr[h], ob[h]);
        }
        if (WITHA) {
            const float den = q2ea + kk2 - 2.0f * dotA;
            float s = dotA * dotA * fast_rcp(den) * inv_scale;
            const bool ok = (j <= iA);
            s = ok ? s : 0.0f;
            if (s > mA) {
                const float mn = s + 24.0f;
                const float c = __expf(mA - mn);
                mA = mn; lA *= c;
                #pragma unroll
                for (int h = 0; h < 16; ++h) oa[h] *= c;
            }
            float p = __expf(s - mA);
            p = ok ? p : 0.0f;
            lA += p;
            #pragma unroll
            for (int h = 0; h < 16; ++h) oa[h] = fmaf(p, vr[h], oa[h]);
        }
    }
}

__device__ __forceinline__ void write_row_hl(
    unsigned short* __restrict__ ah, unsigned short* __restrict__ al,
    float* __restrict__ x2a, int rowidx, size_t off,
    const float (&o)[16], float il)
{
    unsigned short hb[16], lb16[16];
    float s2 = 0.0f;
    #pragma unroll
    for (int h = 0; h < 16; ++h) {
        float v = o[h] * il;
        unsigned short hh = f32_bf16(v);
        hb[h] = hh;
        lb16[h] = f32_bf16(v - bf16_f32(hh));
        s2 = fmaf(v, v, s2);
    }
    #pragma unroll
    for (int q = 0; q < 4; ++q) {
        *(ushort4*)(ah + off + q * 4) =
            make_ushort4(hb[q*4], hb[q*4+1], hb[q*4+2], hb[q*4+3]);
        *(ushort4*)(al + off + q * 4) =
            make_ushort4(lb16[q*4], lb16[q*4+1], lb16[q*4+2], lb16[q*4+3]);
    }
    atomicAdd(&x2a[rowidx], s2);
}

__global__ __launch_bounds__(256) void yat_attention3_kernel(
    const float* __restrict__ qkvT, const float* __restrict__ k2k,
    const float* __restrict__ alphap,
    unsigned short* __restrict__ attn_h, unsigned short* __restrict__ attn_l,
    float* __restrict__ x2a)
{
    // flat LDS: kS [4 tiles x 1024 f] | vS [4 x 1024] | k2S [4 x 64]
    // merge buf (4608 f) reuses the kS region after the final tile barrier
    __shared__ __align__(16) float smem[8448];

    const int tid  = threadIdx.x;
    const int lane = tid & 63;
    const int wid  = tid >> 6;
    const int dsel = wid & 1;
    const int half = wid >> 1;
    const int tau  = blockIdx.x;
    const int d0   = blockIdx.y * 2;
    const int b    = blockIdx.z;
    const int d    = d0 + dsel;

    const int iA = tau * 64 + lane;
    const int iB = (15 - tau) * 64 + lane;
    const int ntiles = 16 - tau;
    const int nsteps = (ntiles + 1) >> 1;

    const float inv_scale = powf(64.0f / log1pf(64.0f), alphap[0]);

    const size_t plane = 16384;
    const float* qpl = qkvT + (size_t)((b * 3 + 0) * 64 + d) * plane;
    const float* kpl = qkvT + (size_t)((b * 3 + 1) * 64 + d) * plane;
    const float* vpl = qkvT + (size_t)((b * 3 + 2) * 64 + d) * plane;
    const float* k2row = k2k + ((size_t)b << 16) + ((size_t)d << 10);

    float* ktile  = smem + (wid << 10);          // 1024 floats per (dsel,half)
    float* vtile  = smem + 4096 + (wid << 10);
    float* k2tile = smem + 8192 + (wid << 6);

    float qa[16], qb[16];
    {
        const float* pa = qpl + (size_t)iA * 16;
        const float* pb = qpl + (size_t)iB * 16;
        #pragma unroll
        for (int h4 = 0; h4 < 4; ++h4) {
            float4 va = *(const float4*)(pa + h4 * 4);
            float4 vb = *(const float4*)(pb + h4 * 4);
            qa[h4*4+0] = va.x; qa[h4*4+1] = va.y;
            qa[h4*4+2] = va.z; qa[h4*4+3] = va.w;
            qb[h4*4+0] = vb.x; qb[h4*4+1] = vb.y;
            qb[h4*4+2] = vb.z; qb[h4*4+3] = vb.w;
        }
    }
    float q2ea = YAT_EPS, q2eb = YAT_EPS;
    #pragma unroll
    for (int h = 0; h < 16; ++h) {
        q2ea = fmaf(qa[h], qa[h], q2ea);
        q2eb = fmaf(qb[h], qb[h], q2eb);
    }

    float mA = -1e30f, lA = 0.0f, mB = -1e30f, lB = 0.0f;
    float oa[16], ob[16];
    #pragma unroll
    for (int h = 0; h < 16; ++h) { oa[h] = 0.0f; ob[h] = 0.0f; }

    for (int step = 0; step < nsteps; ++step) {
        const int jt = step * 2 + half;
        const bool active = (jt < ntiles);
        const int j0 = jt * 64;
        __syncthreads();
        if (active) {
            #pragma unroll
            for (int r = 0; r < 4; ++r) {
                const int f4 = r * 64 + lane;      // 0..255 float4s
                const int row = f4 >> 2, c4 = (f4 & 3) * 4;
                const size_t go = (size_t)(j0 + row) * 16 + c4;
                *(float4*)(ktile + row * 16 + c4) = *(const float4*)(kpl + go);
                *(float4*)(vtile + row * 16 + c4) = *(const float4*)(vpl + go);
            }
            k2tile[lane] = k2row[j0 + lane];
        }
        __syncthreads();
        if (active) {
            if (jt <= tau)
                yat_tile<true>(ktile, vtile, k2tile, j0, iA, iB,
                               qa, qb, q2ea, q2eb, inv_scale,
                               mA, lA, oa, mB, lB, ob);
            else
                yat_tile<false>(ktile, vtile, k2tile, j0, iA, iB,
                                qa, qb, q2ea, q2eb, inv_scale,
                                mA, lA, oa, mB, lB, ob);
        }
    }

    // ---- merge halves ----
    __syncthreads();
    float* mb = smem + ((size_t)(dsel * 64 + lane) * 2) * 18;  // rows A,B
    if (half == 1) {
        #pragma unroll
        for (int h = 0; h < 16; ++h) { mb[h] = oa[h]; mb[18 + h] = ob[h]; }
        mb[16] = mA; mb[17] = lA;
        mb[34] = mB; mb[35] = lB;
    }
    __syncthreads();
    if (half == 0) {
        // row A merge
        float m1 = mb[16], l1 = mb[17];
        float m = fmaxf(mA, m1);
        float c0 = __expf(mA - m), c1 = __expf(m1 - m);
        float lAf = lA * c0 + l1 * c1;
        #pragma unroll
        for (int h = 0; h < 16; ++h) oa[h] = oa[h] * c0 + mb[h] * c1;
        // row B merge
        m1 = mb[34]; l1 = mb[35];
        m = fmaxf(mB, m1);
        c0 = __expf(mB - m); c1 = __expf(m1 - m);
        float lBf = lB * c0 + l1 * c1;
        #pragma unroll
        for (int h = 0; h < 16; ++h) ob[h] = ob[h] * c0 + mb[18 + h] * c1;

        const int rowA = b * 1024 + iA;
        const int rowB = b * 1024 + iB;
        write_row_hl(attn_h, attn_l, x2a, rowA,
                     (size_t)rowA * 1024 + d * 16, oa, 1.0f / lAf);
        write_row_hl(attn_h, attn_l, x2a, rowB,
                     (size_t)rowB * 1024 + d * 16, ob, 1.0f / lBf);
    }
}

// ---------------------------------------------------------------------------
extern "C" void kernel_launch(void* const* d_in, const int* in_sizes, int n_in,
                              void* d_out, int out_size, void* d_ws, size_t ws_size,
                              hipStream_t stream)
{
    const float* x          = (const float*)d_in[0];
    // d_in[1] = causal mask, constant — causality hard-coded
    const float* w_qkv      = (const float*)d_in[2];
    const float* b_qkv      = (const float*)d_in[3];
    const float* alpha_qkv  = (const float*)d_in[4];
    const float* w_proj     = (const float*)d_in[5];
    const float* b_proj     = (const float*)d_in[6];
    const float* alpha_proj = (const float*)d_in[7];
    const float* alpha_attn = (const float*)d_in[8];
    float* out = (float*)d_out;

    float* ws = (float*)d_ws;
    float*          qkvT = ws;                                   // 6291456
    unsigned short* WtQh = (unsigned short*)(ws + 6291456);      // 3072x1024 bf16
    unsigned short* WtQl = (unsigned short*)(ws + 7864320);
    unsigned short* WtPh = (unsigned short*)(ws + 9437184);      // 1024x1024 bf16
    unsigned short* WtPl = (unsigned short*)(ws + 9961472);
    unsigned short* xh   = (unsigned short*)(ws + 10485760);     // 2048x1024 bf16
    unsigned short* xl   = (unsigned short*)(ws + 11534336);
    float* x2x  = ws + 12582912;   // 2048
    float* x2a  = ws + 12584960;   // 2048 (atomic)
    float* k2q  = ws + 12587008;   // 3072 (atomic)
    float* k2p  = ws + 12590080;   // 1024 (atomic)
    float* k2k  = ws + 12591104;   // 131072
    unsigned short* attn_h = WtQh;  // alias: WtQ dead after QKV GEMM
    unsigned short* attn_l = WtQl;

    hipMemsetAsync(x2a, 0, (2048 + 3072 + 1024) * sizeof(float), stream);

    convtrans_kernel<<<dim3(96, 32), dim3(32, 8), 0, stream>>>(
        w_qkv, WtQh, WtQl, 1024, 3072);
    convtrans_kernel<<<dim3(32, 32), dim3(32, 8), 0, stream>>>(
        w_proj, WtPh, WtPl, 1024, 1024);
    conv_hl_kernel<<<2048, 256, 0, stream>>>(x, xh, xl, 524288);
    colsumsq_kernel<<<dim3(12, 16), 256, 0, stream>>>(w_qkv, k2q, 1024, 3072);
    colsumsq_kernel<<<dim3(4, 16),  256, 0, stream>>>(w_proj, k2p, 1024, 1024);
    rowsumsq_kernel<<<512, 256, 0, stream>>>(x, x2x, 1024);

    const float sb_qkv = sqrtf(3072.0f) / log1pf(3072.0f);
    gemm_yat_mfma_kernel<1><<<dim3(24, 32), 256, 0, stream>>>(
        xh, xl, WtQh, WtQl, b_qkv, x2x, k2q, alpha_qkv, qkvT,
        3072, 1024, sb_qkv);

    sumsq16_kernel<<<512, 256, 0, stream>>>(qkvT, k2k);

    yat_attention3_kernel<<<dim3(8, 32, 2), 256, 0, stream>>>(
        qkvT, k2k, alpha_attn, attn_h, attn_l, x2a);

    const float sb_proj = sqrtf(1024.0f) / log1pf(1024.0f);
    gemm_yat_mfma_kernel<0><<<dim3(8, 32), 256, 0, stream>>>(
        attn_h, attn_l, WtPh, WtPl, b_proj, x2a, k2p, alpha_proj, out,
        1024, 1024, sb_proj);
}

// Round 5
// 325.006 us; speedup vs baseline: 2.9925x; 1.1510x over previous
//
#include <hip/hip_runtime.h>
#include <math.h>

#define YAT_EPS (1.0f / 137.0f)

// Logical sizes (fixed): B=2, T=1024, C=1024.
// Attention (faithful to reference transpose): 64 "heads" (d axis),
// per-head dim 16 (h axis), causal, T=1024.
// qkvT layout: [b][s][d][h][t]  (t contiguous; plane of 16384 per (b,s,d))

typedef __bf16 bf16x8 __attribute__((ext_vector_type(8)));
typedef float floatx4 __attribute__((ext_vector_type(4)));

__device__ __forceinline__ float fast_rcp(float x) {
#if __has_builtin(__builtin_amdgcn_rcpf)
    return __builtin_amdgcn_rcpf(x);
#else
    return 1.0f / x;
#endif
}

__device__ __forceinline__ unsigned short f32_bf16(float f) {
    unsigned u = __builtin_bit_cast(unsigned, f);
    u += 0x7fffu + ((u >> 16) & 1u);      // RNE; inputs are finite/normal
    return (unsigned short)(u >> 16);
}
__device__ __forceinline__ float bf16_f32(unsigned short h) {
    unsigned u = ((unsigned)h) << 16;
    return __builtin_bit_cast(float, u);
}

// ---------------------------------------------------------------------------
// Fused: W[K][N] fp32 -> Wt hi/lo [N][K] bf16  +  k2[n] = sum_k W[k][n]^2
// block (32,8), grid (N/32, K/32).  k2 accumulated via per-column
// half-wave reduction + one atomicAdd per (column, k-block).
// ---------------------------------------------------------------------------
__global__ void convtrans_kernel(
    const float* __restrict__ W, unsigned short* __restrict__ th,
    unsigned short* __restrict__ tl, float* __restrict__ k2, int K, int N)
{
    __shared__ float t[32][33];
    int tx = threadIdx.x, ty = threadIdx.y;
    int n0 = blockIdx.x * 32, k0 = blockIdx.y * 32;
    #pragma unroll
    for (int r = 0; r < 4; ++r)
        t[ty + r * 8][tx] = W[(size_t)(k0 + ty + r * 8) * N + n0 + tx];
    __syncthreads();
    #pragma unroll
    for (int r = 0; r < 4; ++r) {
        int nl = ty + r * 8;
        float v = t[tx][nl];
        unsigned short h = f32_bf16(v);
        th[(size_t)(n0 + nl) * K + k0 + tx] = h;
        tl[(size_t)(n0 + nl) * K + k0 + tx] = f32_bf16(v - bf16_f32(h));
        float s = v * v;
        #pragma unroll
        for (int m = 16; m > 0; m >>= 1) s += __shfl_xor(s, m, 32);
        if (tx == 0) atomicAdd(&k2[n0 + nl], s);
    }
}

// ---------------------------------------------------------------------------
// Fused: x row -> bf16 hi/lo + x2[row].  One block (256 thr) per 1024-f row.
// ---------------------------------------------------------------------------
__global__ __launch_bounds__(256) void convx_kernel(
    const float* __restrict__ x, unsigned short* __restrict__ hi,
    unsigned short* __restrict__ lo, float* __restrict__ x2x)
{
    __shared__ float red[4];
    const int row = blockIdx.x, tid = threadIdx.x;
    float4 v = *(const float4*)(x + (size_t)row * 1024 + tid * 4);
    float vv[4] = {v.x, v.y, v.z, v.w};
    unsigned short hh[4], ll[4];
    float s = 0.0f;
    #pragma unroll
    for (int e = 0; e < 4; ++e) {
        hh[e] = f32_bf16(vv[e]);
        ll[e] = f32_bf16(vv[e] - bf16_f32(hh[e]));
        s = fmaf(vv[e], vv[e], s);
    }
    *(ushort4*)(hi + (size_t)row * 1024 + tid * 4) =
        make_ushort4(hh[0], hh[1], hh[2], hh[3]);
    *(ushort4*)(lo + (size_t)row * 1024 + tid * 4) =
        make_ushort4(ll[0], ll[1], ll[2], ll[3]);
    #pragma unroll
    for (int off = 32; off > 0; off >>= 1) s += __shfl_down(s, off, 64);
    if ((tid & 63) == 0) red[tid >> 6] = s;
    __syncthreads();
    if (tid == 0) x2x[row] = red[0] + red[1] + red[2] + red[3];
}

// ---------------------------------------------------------------------------
// k2k[b][d][t] = sum_h K[b][d][h][t]^2 over the K planes of qkvT (new layout)
// ---------------------------------------------------------------------------
__global__ __launch_bounds__(256) void sumsq16_kernel(
    const float* __restrict__ qkvT, float* __restrict__ k2k)
{
    int idx = blockIdx.x * 256 + threadIdx.x;   // b*65536 + d*1024 + t
    int b = idx >> 16;
    int d = (idx >> 10) & 63;
    int t = idx & 1023;
    const float* pl = qkvT + ((size_t)((b * 3 + 1) * 64 + d)) * 16384 + t;
    float s = 0.0f;
    #pragma unroll
    for (int h = 0; h < 16; ++h) {
        float v = pl[h * 1024];
        s = fmaf(v, v, s);
    }
    k2k[idx] = s;
}

// ---------------------------------------------------------------------------
// Split-bf16 MFMA YAT-dense GEMM.
// MODE 0: row-major store.  MODE 1: store to qkvT[b][s][d][h][t] (coalesced:
// a C-tile column has 16 consecutive t -> float4 per thread, 64B per column).
// ---------------------------------------------------------------------------
template <int MODE>
__global__ __launch_bounds__(256) void gemm_yat_mfma_kernel(
    const unsigned short* __restrict__ Ah, const unsigned short* __restrict__ Al,
    const unsigned short* __restrict__ Bh, const unsigned short* __restrict__ Bl,
    const float* __restrict__ bias, const float* __restrict__ x2,
    const float* __restrict__ k2, const float* __restrict__ alphap,
    float* __restrict__ out, int N, int K, float scale_base)
{
    __shared__ __align__(16) unsigned short sbuf[12288];

    const int tid = threadIdx.x;
    const int w = tid >> 6, l = tid & 63;
    const int lane16 = l & 15, quad = l >> 4;
    const int wm = w & 1, wn = w >> 1;
    const int m0 = blockIdx.y * 64, n0 = blockIdx.x * 128;

    floatx4 acc[2][4];
    #pragma unroll
    for (int tm = 0; tm < 2; ++tm)
        #pragma unroll
        for (int tn = 0; tn < 4; ++tn)
            acc[tm][tn] = (floatx4){0.f, 0.f, 0.f, 0.f};

    for (int k0 = 0; k0 < K; k0 += 32) {
        __syncthreads();
        #pragma unroll
        for (int i = 0; i < 6; ++i) {
            const int o = (i * 4 + w) * 1024;
            const unsigned short* gp;
            if (o < 8192) {
                const unsigned short* g = (o < 4096) ? Ah : Al;
                const int oo = o & 4095;
                gp = g + (size_t)(m0 + (oo >> 6) + (l >> 2)) * K + k0 + (l & 3) * 8;
            } else {
                const int ob = o - 8192;
                const unsigned short* g = (ob < 8192) ? Bh : Bl;
                const int oo = ob & 8191;
                gp = g + (size_t)(n0 + (oo >> 6) + (l >> 2)) * K + k0 + (l & 3) * 8;
            }
            __builtin_amdgcn_global_load_lds(
                (const __attribute__((address_space(1))) unsigned int*)gp,
                (__attribute__((address_space(3))) unsigned int*)((char*)sbuf + o),
                16, 0, 0);
        }
        __syncthreads();

        bf16x8 afh[2], afl[2], bfh[4], bfl[4];
        #pragma unroll
        for (int tm = 0; tm < 2; ++tm) {
            const int base = (wm * 32 + tm * 16 + lane16) * 32 + quad * 8;
            afh[tm] = *(const bf16x8*)(sbuf + base);
            afl[tm] = *(const bf16x8*)(sbuf + 2048 + base);
        }
        #pragma unroll
        for (int tn = 0; tn < 4; ++tn) {
            const int nb = (wn * 64 + tn * 16 + lane16) * 32 + quad * 8;
            bfh[tn] = *(const bf16x8*)(sbuf + 4096 + nb);
            bfl[tn] = *(const bf16x8*)(sbuf + 8192 + nb);
        }
        #pragma unroll
        for (int tm = 0; tm < 2; ++tm)
            #pragma unroll
            for (int tn = 0; tn < 4; ++tn) {
                acc[tm][tn] = __builtin_amdgcn_mfma_f32_16x16x32_bf16(
                    afh[tm], bfh[tn], acc[tm][tn], 0, 0, 0);
                acc[tm][tn] = __builtin_amdgcn_mfma_f32_16x16x32_bf16(
                    afh[tm], bfl[tn], acc[tm][tn], 0, 0, 0);
                acc[tm][tn] = __builtin_amdgcn_mfma_f32_16x16x32_bf16(
                    afl[tm], bfh[tn], acc[tm][tn], 0, 0, 0);
            }
    }

    const float scale = powf(scale_base, alphap[0]);
    #pragma unroll
    for (int tm = 0; tm < 2; ++tm) {
        #pragma unroll
        for (int tn = 0; tn < 4; ++tn) {
            const int n = n0 + wn * 64 + tn * 16 + lane16;
            const float kk = k2[n];
            const float bb = bias[n];
            const int mrow = m0 + wm * 32 + tm * 16 + quad * 4;
            float4 r4;
            float* rp = (float*)&r4;
            #pragma unroll
            for (int r = 0; r < 4; ++r) {
                const float y = acc[tm][tn][r];
                const float den = x2[mrow + r] + kk - 2.0f * y + YAT_EPS;
                rp[r] = y * y / den * scale + bb;
            }
            if (MODE == 0) {
                #pragma unroll
                for (int r = 0; r < 4; ++r)
                    out[(size_t)(mrow + r) * N + n] = rp[r];
            } else {
                const int s = n >> 10, hh = (n >> 6) & 15, dd = n & 63;
                const int bb2 = m0 >> 10;              // tile is within one b
                const int t0 = (mrow & 1023);
                *(float4*)&out[((size_t)((bb2 * 3 + s) * 64 + dd) * 16 + hh)
                               * 1024 + t0] = r4;
            }
        }
    }
}

// ---------------------------------------------------------------------------
// Attention v4: one d per block; 4 waves = 4 j-quarters, each with PRIVATE
// LDS K/V tile and private online-softmax state -> NO barriers in main loop.
// Wave = 64 lanes <-> 64 q-rows; 2 rows/lane from paired i-tiles (tau,15-tau).
// Quarter q processes j-tiles jt % 4 == q.  2-barrier LDS merge at the end.
// Grid = 8 x 64 x 2 = 1024 blocks x 4 waves.
// ---------------------------------------------------------------------------
template <bool WITHA>
__device__ __forceinline__ void yat_tile(
    const float* __restrict__ kT, const float* __restrict__ vT,
    const float* __restrict__ k2T, int j0, int iA, int iB,
    const float (&qa)[16], const float (&qb)[16],
    float q2ea, float q2eb, float inv_scale,
    float& mA, float& lA, float (&oa)[16],
    float& mB, float& lB, float (&ob)[16])
{
    #pragma unroll 2
    for (int jj = 0; jj < 64; ++jj) {
        const int j = j0 + jj;
        const float* kp = kT + jj * 16;
        const float* vp = vT + jj * 16;
        float kr[16], vr[16];
        #pragma unroll
        for (int h4 = 0; h4 < 4; ++h4) {
            float4 kv = *(const float4*)(kp + h4 * 4);
            float4 vv = *(const float4*)(vp + h4 * 4);
            kr[h4*4+0] = kv.x; kr[h4*4+1] = kv.y;
            kr[h4*4+2] = kv.z; kr[h4*4+3] = kv.w;
            vr[h4*4+0] = vv.x; vr[h4*4+1] = vv.y;
            vr[h4*4+2] = vv.z; vr[h4*4+3] = vv.w;
        }
        const float kk2 = k2T[jj];

        float dotB = 0.0f;
        #pragma unroll
        for (int h = 0; h < 16; ++h) dotB = fmaf(qb[h], kr[h], dotB);
        float dotA = 0.0f;
        if (WITHA) {
            #pragma unroll
            for (int h = 0; h < 16; ++h) dotA = fmaf(qa[h], kr[h], dotA);
        }

        {   // row B
            const float den = q2eb + kk2 - 2.0f * dotB;
            float s = dotB * dotB * fast_rcp(den) * inv_scale;
            const bool ok = (j <= iB);
            s = ok ? s : 0.0f;
            if (s > mB) {
                const float mn = s + 24.0f;
                const float c = __expf(mB - mn);
                mB = mn; lB *= c;
                #pragma unroll
                for (int h = 0; h < 16; ++h) ob[h] *= c;
            }
            float p = __expf(s - mB);
            p = ok ? p : 0.0f;
            lB += p;
            #pragma unroll
            for (int h = 0; h < 16; ++h) ob[h] = fmaf(p, vr[h], ob[h]);
        }
        if (WITHA) {
            const float den = q2ea + kk2 - 2.0f * dotA;
            float s = dotA * dotA * fast_rcp(den) * inv_scale;
            const bool ok = (j <= iA);
            s = ok ? s : 0.0f;
            if (s > mA) {
                const float mn = s + 24.0f;
                const float c = __expf(mA - mn);
                mA = mn; lA *= c;
                #pragma unroll
                for (int h = 0; h < 16; ++h) oa[h] *= c;
            }
            float p = __expf(s - mA);
            p = ok ? p : 0.0f;
            lA += p;
            #pragma unroll
            for (int h = 0; h < 16; ++h) oa[h] = fmaf(p, vr[h], oa[h]);
        }
    }
}

__device__ __forceinline__ void write_row_hl(
    unsigned short* __restrict__ ah, unsigned short* __restrict__ al,
    float* __restrict__ x2a, int rowidx, size_t off,
    const float (&o)[16], float il)
{
    unsigned short hb[16], lb16[16];
    float s2 = 0.0f;
    #pragma unroll
    for (int h = 0; h < 16; ++h) {
        float v = o[h] * il;
        unsigned short hh = f32_bf16(v);
        hb[h] = hh;
        lb16[h] = f32_bf16(v - bf16_f32(hh));
        s2 = fmaf(v, v, s2);
    }
    #pragma unroll
    for (int q = 0; q < 4; ++q) {
        *(ushort4*)(ah + off + q * 4) =
            make_ushort4(hb[q*4], hb[q*4+1], hb[q*4+2], hb[q*4+3]);
        *(ushort4*)(al + off + q * 4) =
            make_ushort4(lb16[q*4], lb16[q*4+1], lb16[q*4+2], lb16[q*4+3]);
    }
    atomicAdd(&x2a[rowidx], s2);
}

__global__ __launch_bounds__(256) void yat_attention4_kernel(
    const float* __restrict__ qkvT, const float* __restrict__ k2k,
    const float* __restrict__ alphap,
    unsigned short* __restrict__ attn_h, unsigned short* __restrict__ attn_l,
    float* __restrict__ x2a)
{
    // per-wave region: ktile 1024 f | vtile 1024 f | k2tile 64 f  = 2112 f
    // merge buffer (3*64*37 = 7104 f) aliases the tile regions post-barrier
    __shared__ __align__(16) float smem[8448];

    const int tid  = threadIdx.x;
    const int lane = tid & 63;
    const int q    = tid >> 6;          // j-quarter 0..3
    const int tau  = blockIdx.x;        // 0..7
    const int d    = blockIdx.y;        // 0..63
    const int b    = blockIdx.z;

    const int iA = tau * 64 + lane;
    const int iB = (15 - tau) * 64 + lane;
    const int ntiles = 16 - tau;        // j-tiles 0 .. 15-tau

    const float inv_scale = powf(64.0f / log1pf(64.0f), alphap[0]);

    const size_t plane = 16384;
    const float* qpl = qkvT + (size_t)((b * 3 + 0) * 64 + d) * plane;
    const float* kpl = qkvT + (size_t)((b * 3 + 1) * 64 + d) * plane;
    const float* vpl = qkvT + (size_t)((b * 3 + 2) * 64 + d) * plane;
    const float* k2row = k2k + ((size_t)b << 16) + ((size_t)d << 10);

    float* ktile  = smem + q * 2112;
    float* vtile  = ktile + 1024;
    float* k2tile = vtile + 1024;

    // q rows: q[i][h] = qpl[h*1024 + i]; lanes -> consecutive i (coalesced)
    float qa[16], qb[16];
    #pragma unroll
    for (int h = 0; h < 16; ++h) {
        qa[h] = qpl[h * 1024 + iA];
        qb[h] = qpl[h * 1024 + iB];
    }
    float q2ea = YAT_EPS, q2eb = YAT_EPS;
    #pragma unroll
    for (int h = 0; h < 16; ++h) {
        q2ea = fmaf(qa[h], qa[h], q2ea);
        q2eb = fmaf(qb[h], qb[h], q2eb);
    }

    float mA = -1e30f, lA = 0.0f, mB = -1e30f, lB = 0.0f;
    float oa[16], ob[16];
    #pragma unroll
    for (int h = 0; h < 16; ++h) { oa[h] = 0.0f; ob[h] = 0.0f; }

    for (int jt = q; jt < ntiles; jt += 4) {
        const int j0 = jt * 64;
        // stage K/V tile: global [h][t-contig] -> LDS [j][h] (pitch 16)
        #pragma unroll
        for (int r = 0; r < 4; ++r) {
            const int idx = r * 64 + lane;       // 0..255
            const int h = idx >> 4;
            const int j4 = (idx & 15) * 4;
            float4 kv = *(const float4*)(kpl + h * 1024 + j0 + j4);
            float4 vv = *(const float4*)(vpl + h * 1024 + j0 + j4);
            ktile[(j4 + 0) * 16 + h] = kv.x;
            ktile[(j4 + 1) * 16 + h] = kv.y;
            ktile[(j4 + 2) * 16 + h] = kv.z;
            ktile[(j4 + 3) * 16 + h] = kv.w;
            vtile[(j4 + 0) * 16 + h] = vv.x;
            vtile[(j4 + 1) * 16 + h] = vv.y;
            vtile[(j4 + 2) * 16 + h] = vv.z;
            vtile[(j4 + 3) * 16 + h] = vv.w;
        }
        k2tile[lane] = k2row[j0 + lane];
        // wave-private LDS: compiler inserts the lgkm wait; no barrier needed
        if (jt <= tau)
            yat_tile<true>(ktile, vtile, k2tile, j0, iA, iB,
                           qa, qb, q2ea, q2eb, inv_scale,
                           mA, lA, oa, mB, lB, ob);
        else
            yat_tile<false>(ktile, vtile, k2tile, j0, iA, iB,
                            qa, qb, q2ea, q2eb, inv_scale,
                            mA, lA, oa, mB, lB, ob);
    }

    // ---- merge 4 quarters ----
    __syncthreads();
    if (q > 0) {
        float* mb = smem + ((q - 1) * 64 + lane) * 37;
        #pragma unroll
        for (int h = 0; h < 16; ++h) { mb[h] = oa[h]; mb[18 + h] = ob[h]; }
        mb[16] = mA; mb[17] = lA;
        mb[34] = mB; mb[35] = lB;
    }
    __syncthreads();
    if (q == 0) {
        #pragma unroll
        for (int qq = 0; qq < 3; ++qq) {
            const float* mb = smem + (qq * 64 + lane) * 37;
            // row A
            float m1 = mb[16], l1 = mb[17];
            float m = fmaxf(mA, m1);
            float c0 = __expf(mA - m), c1 = __expf(m1 - m);
            lA = lA * c0 + l1 * c1;
            #pragma unroll
            for (int h = 0; h < 16; ++h) oa[h] = oa[h] * c0 + mb[h] * c1;
            mA = m;
            // row B
            m1 = mb[34]; l1 = mb[35];
            m = fmaxf(mB, m1);
            c0 = __expf(mB - m); c1 = __expf(m1 - m);
            lB = lB * c0 + l1 * c1;
            #pragma unroll
            for (int h = 0; h < 16; ++h) ob[h] = ob[h] * c0 + mb[18 + h] * c1;
            mB = m;
        }
        const int rowA = b * 1024 + iA;
        const int rowB = b * 1024 + iB;
        write_row_hl(attn_h, attn_l, x2a, rowA,
                     (size_t)rowA * 1024 + d * 16, oa, 1.0f / lA);
        write_row_hl(attn_h, attn_l, x2a, rowB,
                     (size_t)rowB * 1024 + d * 16, ob, 1.0f / lB);
    }
}

// ---------------------------------------------------------------------------
extern "C" void kernel_launch(void* const* d_in, const int* in_sizes, int n_in,
                              void* d_out, int out_size, void* d_ws, size_t ws_size,
                              hipStream_t stream)
{
    const float* x          = (const float*)d_in[0];
    // d_in[1] = causal mask, constant — causality hard-coded
    const float* w_qkv      = (const float*)d_in[2];
    const float* b_qkv      = (const float*)d_in[3];
    const float* alpha_qkv  = (const float*)d_in[4];
    const float* w_proj     = (const float*)d_in[5];
    const float* b_proj     = (const float*)d_in[6];
    const float* alpha_proj = (const float*)d_in[7];
    const float* alpha_attn = (const float*)d_in[8];
    float* out = (float*)d_out;

    float* ws = (float*)d_ws;
    float*          qkvT = ws;                                   // 6291456
    unsigned short* WtQh = (unsigned short*)(ws + 6291456);      // 3072x1024 bf16
    unsigned short* WtQl = (unsigned short*)(ws + 7864320);
    unsigned short* WtPh = (unsigned short*)(ws + 9437184);      // 1024x1024 bf16
    unsigned short* WtPl = (unsigned short*)(ws + 9961472);
    unsigned short* xh   = (unsigned short*)(ws + 10485760);     // 2048x1024 bf16
    unsigned short* xl   = (unsigned short*)(ws + 11534336);
    float* x2x  = ws + 12582912;   // 2048
    float* x2a  = ws + 12584960;   // 2048 (atomic)
    float* k2q  = ws + 12587008;   // 3072 (atomic)
    float* k2p  = ws + 12590080;   // 1024 (atomic)
    float* k2k  = ws + 12591104;   // 131072
    unsigned short* attn_h = WtQh;  // alias: WtQ dead after QKV GEMM
    unsigned short* attn_l = WtQl;

    hipMemsetAsync(x2a, 0, (2048 + 3072 + 1024) * sizeof(float), stream);

    convtrans_kernel<<<dim3(96, 32), dim3(32, 8), 0, stream>>>(
        w_qkv, WtQh, WtQl, k2q, 1024, 3072);
    convtrans_kernel<<<dim3(32, 32), dim3(32, 8), 0, stream>>>(
        w_proj, WtPh, WtPl, k2p, 1024, 1024);
    convx_kernel<<<2048, 256, 0, stream>>>(x, xh, xl, x2x);

    const float sb_qkv = sqrtf(3072.0f) / log1pf(3072.0f);
    gemm_yat_mfma_kernel<1><<<dim3(24, 32), 256, 0, stream>>>(
        xh, xl, WtQh, WtQl, b_qkv, x2x, k2q, alpha_qkv, qkvT,
        3072, 1024, sb_qkv);

    sumsq16_kernel<<<512, 256, 0, stream>>>(qkvT, k2k);

    yat_attention4_kernel<<<dim3(8, 64, 2), 256, 0, stream>>>(
        qkvT, k2k, alpha_attn, attn_h, attn_l, x2a);

    const float sb_proj = sqrtf(1024.0f) / log1pf(1024.0f);
    gemm_yat_mfma_kernel<0><<<dim3(8, 32), 256, 0, stream>>>(
        attn_h, attn_l, WtPh, WtPl, b_proj, x2a, k2p, alpha_proj, out,
        1024, 1024, sb_proj);
}

// Round 6
// 308.308 us; speedup vs baseline: 3.1546x; 1.0542x over previous
//
#include <hip/hip_runtime.h>
#include <math.h>

#define YAT_EPS (1.0f / 137.0f)

// Logical sizes (fixed): B=2, T=1024, C=1024.
// Attention (faithful to reference transpose): 64 "heads" (d axis),
// per-head dim 16 (h axis), causal, T=1024.
// qkvT layout: [b][s][d][h][t]  (t contiguous; plane of 16384 per (b,s,d))

typedef __bf16 bf16x8 __attribute__((ext_vector_type(8)));
typedef float floatx4 __attribute__((ext_vector_type(4)));

__device__ __forceinline__ float fast_rcp(float x) {
#if __has_builtin(__builtin_amdgcn_rcpf)
    return __builtin_amdgcn_rcpf(x);
#else
    return 1.0f / x;
#endif
}
__device__ __forceinline__ float fast_exp2(float x) {
#if __has_builtin(__builtin_amdgcn_exp2f)
    return __builtin_amdgcn_exp2f(x);
#else
    return exp2f(x);
#endif
}

__device__ __forceinline__ unsigned short f32_bf16(float f) {
    unsigned u = __builtin_bit_cast(unsigned, f);
    u += 0x7fffu + ((u >> 16) & 1u);      // RNE; inputs are finite/normal
    return (unsigned short)(u >> 16);
}
__device__ __forceinline__ float bf16_f32(unsigned short h) {
    unsigned u = ((unsigned)h) << 16;
    return __builtin_bit_cast(float, u);
}

// ---------------------------------------------------------------------------
// Fused: W[K][N] fp32 -> Wt hi/lo [N][K] bf16  +  k2[n] = sum_k W[k][n]^2
// ---------------------------------------------------------------------------
__global__ void convtrans_kernel(
    const float* __restrict__ W, unsigned short* __restrict__ th,
    unsigned short* __restrict__ tl, float* __restrict__ k2, int K, int N)
{
    __shared__ float t[32][33];
    int tx = threadIdx.x, ty = threadIdx.y;
    int n0 = blockIdx.x * 32, k0 = blockIdx.y * 32;
    #pragma unroll
    for (int r = 0; r < 4; ++r)
        t[ty + r * 8][tx] = W[(size_t)(k0 + ty + r * 8) * N + n0 + tx];
    __syncthreads();
    #pragma unroll
    for (int r = 0; r < 4; ++r) {
        int nl = ty + r * 8;
        float v = t[tx][nl];
        unsigned short h = f32_bf16(v);
        th[(size_t)(n0 + nl) * K + k0 + tx] = h;
        tl[(size_t)(n0 + nl) * K + k0 + tx] = f32_bf16(v - bf16_f32(h));
        float s = v * v;
        #pragma unroll
        for (int m = 16; m > 0; m >>= 1) s += __shfl_xor(s, m, 32);
        if (tx == 0) atomicAdd(&k2[n0 + nl], s);
    }
}

// ---------------------------------------------------------------------------
// Fused: x row -> bf16 hi/lo + x2[row].  One block (256 thr) per 1024-f row.
// ---------------------------------------------------------------------------
__global__ __launch_bounds__(256) void convx_kernel(
    const float* __restrict__ x, unsigned short* __restrict__ hi,
    unsigned short* __restrict__ lo, float* __restrict__ x2x)
{
    __shared__ float red[4];
    const int row = blockIdx.x, tid = threadIdx.x;
    float4 v = *(const float4*)(x + (size_t)row * 1024 + tid * 4);
    float vv[4] = {v.x, v.y, v.z, v.w};
    unsigned short hh[4], ll[4];
    float s = 0.0f;
    #pragma unroll
    for (int e = 0; e < 4; ++e) {
        hh[e] = f32_bf16(vv[e]);
        ll[e] = f32_bf16(vv[e] - bf16_f32(hh[e]));
        s = fmaf(vv[e], vv[e], s);
    }
    *(ushort4*)(hi + (size_t)row * 1024 + tid * 4) =
        make_ushort4(hh[0], hh[1], hh[2], hh[3]);
    *(ushort4*)(lo + (size_t)row * 1024 + tid * 4) =
        make_ushort4(ll[0], ll[1], ll[2], ll[3]);
    #pragma unroll
    for (int off = 32; off > 0; off >>= 1) s += __shfl_down(s, off, 64);
    if ((tid & 63) == 0) red[tid >> 6] = s;
    __syncthreads();
    if (tid == 0) x2x[row] = red[0] + red[1] + red[2] + red[3];
}

// ---------------------------------------------------------------------------
// k2k[b][d][t] = sum_h K[b][d][h][t]^2 over the K planes of qkvT
// ---------------------------------------------------------------------------
__global__ __launch_bounds__(256) void sumsq16_kernel(
    const float* __restrict__ qkvT, float* __restrict__ k2k)
{
    int idx = blockIdx.x * 256 + threadIdx.x;   // b*65536 + d*1024 + t
    int b = idx >> 16;
    int d = (idx >> 10) & 63;
    int t = idx & 1023;
    const float* pl = qkvT + ((size_t)((b * 3 + 1) * 64 + d)) * 16384 + t;
    float s = 0.0f;
    #pragma unroll
    for (int h = 0; h < 16; ++h) {
        float v = pl[h * 1024];
        s = fmaf(v, v, s);
    }
    k2k[idx] = s;
}

// ---------------------------------------------------------------------------
// Split-bf16 MFMA YAT-dense GEMM, templated m-tile.
// Tile BM(m) x 128(n), BK=32, 256 threads = 4 waves, wave = (BM/2)x64
// quadrant of TM x 4 16x16 C-tiles.  3 MFMAs per tile (hi*hi+hi*lo+lo*hi).
// MODE 0: row-major store.  MODE 1: store to qkvT[b][s][d][h][t] (coalesced).
// ---------------------------------------------------------------------------
template <int BM, int MODE>
__global__ __launch_bounds__(256) void gemm_yat_mfma_kernel(
    const unsigned short* __restrict__ Ah, const unsigned short* __restrict__ Al,
    const unsigned short* __restrict__ Bh, const unsigned short* __restrict__ Bl,
    const float* __restrict__ bias, const float* __restrict__ x2,
    const float* __restrict__ k2, const float* __restrict__ alphap,
    float* __restrict__ out, int N, int K, float scale_base)
{
    constexpr int TM = BM / 32;                 // 16-row tiles per wave (m)
    constexpr int NI = (BM * 128 + 16384) / 4096;  // staging instrs / wave
    __shared__ __align__(16) unsigned short sbuf[BM * 64 + 8192];

    const int tid = threadIdx.x;
    const int w = tid >> 6, l = tid & 63;
    const int lane16 = l & 15, quad = l >> 4;
    const int wm = w & 1, wn = w >> 1;
    const int m0 = blockIdx.y * BM, n0 = blockIdx.x * 128;

    floatx4 acc[TM][4];
    #pragma unroll
    for (int tm = 0; tm < TM; ++tm)
        #pragma unroll
        for (int tn = 0; tn < 4; ++tn)
            acc[tm][tn] = (floatx4){0.f, 0.f, 0.f, 0.f};

    for (int k0 = 0; k0 < K; k0 += 32) {
        __syncthreads();
        #pragma unroll
        for (int i = 0; i < NI; ++i) {
            const int o = (i * 4 + w) * 1024;   // byte offset (wave-uniform)
            const unsigned short* gp;
            if (o < BM * 128) {                  // A region (hi | lo)
                const unsigned short* g = (o < BM * 64) ? Ah : Al;
                const int oo = (o < BM * 64) ? o : o - BM * 64;
                gp = g + (size_t)(m0 + (oo >> 6) + (l >> 2)) * K + k0 + (l & 3) * 8;
            } else {                             // B region (hi | lo)
                const int ob = o - BM * 128;
                const unsigned short* g = (ob < 8192) ? Bh : Bl;
                const int oo = ob & 8191;
                gp = g + (size_t)(n0 + (oo >> 6) + (l >> 2)) * K + k0 + (l & 3) * 8;
            }
            __builtin_amdgcn_global_load_lds(
                (const __attribute__((address_space(1))) unsigned int*)gp,
                (__attribute__((address_space(3))) unsigned int*)((char*)sbuf + o),
                16, 0, 0);
        }
        __syncthreads();

        bf16x8 afh[TM], afl[TM], bfh[4], bfl[4];
        #pragma unroll
        for (int tm = 0; tm < TM; ++tm) {
            const int base = (wm * (BM / 2) + tm * 16 + lane16) * 32 + quad * 8;
            afh[tm] = *(const bf16x8*)(sbuf + base);
            afl[tm] = *(const bf16x8*)(sbuf + BM * 32 + base);
        }
        #pragma unroll
        for (int tn = 0; tn < 4; ++tn) {
            const int nb = (wn * 64 + tn * 16 + lane16) * 32 + quad * 8;
            bfh[tn] = *(const bf16x8*)(sbuf + BM * 64 + nb);
            bfl[tn] = *(const bf16x8*)(sbuf + BM * 64 + 4096 + nb);
        }
        #pragma unroll
        for (int tm = 0; tm < TM; ++tm)
            #pragma unroll
            for (int tn = 0; tn < 4; ++tn) {
                acc[tm][tn] = __builtin_amdgcn_mfma_f32_16x16x32_bf16(
                    afh[tm], bfh[tn], acc[tm][tn], 0, 0, 0);
                acc[tm][tn] = __builtin_amdgcn_mfma_f32_16x16x32_bf16(
                    afh[tm], bfl[tn], acc[tm][tn], 0, 0, 0);
                acc[tm][tn] = __builtin_amdgcn_mfma_f32_16x16x32_bf16(
                    afl[tm], bfh[tn], acc[tm][tn], 0, 0, 0);
            }
    }

    const float scale = powf(scale_base, alphap[0]);
    #pragma unroll
    for (int tm = 0; tm < TM; ++tm) {
        #pragma unroll
        for (int tn = 0; tn < 4; ++tn) {
            const int n = n0 + wn * 64 + tn * 16 + lane16;
            const float kk = k2[n];
            const float bb = bias[n];
            const int mrow = m0 + wm * (BM / 2) + tm * 16 + quad * 4;
            float4 r4;
            float* rp = (float*)&r4;
            #pragma unroll
            for (int r = 0; r < 4; ++r) {
                const float y = acc[tm][tn][r];
                const float den = x2[mrow + r] + kk - 2.0f * y + YAT_EPS;
                rp[r] = y * y / den * scale + bb;
            }
            if (MODE == 0) {
                #pragma unroll
                for (int r = 0; r < 4; ++r)
                    out[(size_t)(mrow + r) * N + n] = rp[r];
            } else {
                const int s = n >> 10, hh = (n >> 6) & 15, dd = n & 63;
                const int bb2 = m0 >> 10;              // tile within one b
                const int t0 = (mrow & 1023);
                *(float4*)&out[((size_t)((bb2 * 3 + s) * 64 + dd) * 16 + hh)
                               * 1024 + t0] = r4;
            }
        }
    }
}

// ---------------------------------------------------------------------------
// Attention v5: one d per block; 4 waves = 4 j-quarters, each with PRIVATE
// LDS K/V tile and private online-softmax state -> no barriers in main loop.
// Staging: lane <-> j (row): 16 coalesced wave-loads per array, then
// 4 x ds_write_b128 per array at ktile[lane*16+..] (2-way banks = free).
// Softmax in exp2 domain (log2e folded into inv_scale).
// ---------------------------------------------------------------------------
template <bool WITHA>
__device__ __forceinline__ void yat_tile(
    const float* __restrict__ kT, const float* __restrict__ vT,
    const float* __restrict__ k2T, int j0, int iA, int iB,
    const float (&qa)[16], const float (&qb)[16],
    float q2ea, float q2eb, float inv_scale,
    float& mA, float& lA, float (&oa)[16],
    float& mB, float& lB, float (&ob)[16])
{
    #pragma unroll 2
    for (int jj = 0; jj < 64; ++jj) {
        const int j = j0 + jj;
        const float* kp = kT + jj * 16;
        const float* vp = vT + jj * 16;
        float kr[16], vr[16];
        #pragma unroll
        for (int h4 = 0; h4 < 4; ++h4) {
            float4 kv = *(const float4*)(kp + h4 * 4);
            float4 vv = *(const float4*)(vp + h4 * 4);
            kr[h4*4+0] = kv.x; kr[h4*4+1] = kv.y;
            kr[h4*4+2] = kv.z; kr[h4*4+3] = kv.w;
            vr[h4*4+0] = vv.x; vr[h4*4+1] = vv.y;
            vr[h4*4+2] = vv.z; vr[h4*4+3] = vv.w;
        }
        const float kk2 = k2T[jj];

        float dotB = 0.0f;
        #pragma unroll
        for (int h = 0; h < 16; ++h) dotB = fmaf(qb[h], kr[h], dotB);
        float dotA = 0.0f;
        if (WITHA) {
            #pragma unroll
            for (int h = 0; h < 16; ++h) dotA = fmaf(qa[h], kr[h], dotA);
        }

        {   // row B
            const float den = q2eb + kk2 - 2.0f * dotB;
            float s = dotB * dotB * fast_rcp(den) * inv_scale;  // log2 domain
            const bool ok = (j <= iB);
            s = ok ? s : 0.0f;
            if (s > mB) {
                const float mn = s + 30.0f;
                const float c = fast_exp2(mB - mn);
                mB = mn; lB *= c;
                #pragma unroll
                for (int h = 0; h < 16; ++h) ob[h] *= c;
            }
            float p = fast_exp2(s - mB);
            p = ok ? p : 0.0f;
            lB += p;
            #pragma unroll
            for (int h = 0; h < 16; ++h) ob[h] = fmaf(p, vr[h], ob[h]);
        }
        if (WITHA) {
            const float den = q2ea + kk2 - 2.0f * dotA;
            float s = dotA * dotA * fast_rcp(den) * inv_scale;
            const bool ok = (j <= iA);
            s = ok ? s : 0.0f;
            if (s > mA) {
                const float mn = s + 30.0f;
                const float c = fast_exp2(mA - mn);
                mA = mn; lA *= c;
                #pragma unroll
                for (int h = 0; h < 16; ++h) oa[h] *= c;
            }
            float p = fast_exp2(s - mA);
            p = ok ? p : 0.0f;
            lA += p;
            #pragma unroll
            for (int h = 0; h < 16; ++h) oa[h] = fmaf(p, vr[h], oa[h]);
        }
    }
}

__device__ __forceinline__ void write_row_hl(
    unsigned short* __restrict__ ah, unsigned short* __restrict__ al,
    float* __restrict__ x2a, int rowidx, size_t off,
    const float (&o)[16], float il)
{
    unsigned short hb[16], lb16[16];
    float s2 = 0.0f;
    #pragma unroll
    for (int h = 0; h < 16; ++h) {
        float v = o[h] * il;
        unsigned short hh = f32_bf16(v);
        hb[h] = hh;
        lb16[h] = f32_bf16(v - bf16_f32(hh));
        s2 = fmaf(v, v, s2);
    }
    #pragma unroll
    for (int q = 0; q < 4; ++q) {
        *(ushort4*)(ah + off + q * 4) =
            make_ushort4(hb[q*4], hb[q*4+1], hb[q*4+2], hb[q*4+3]);
        *(ushort4*)(al + off + q * 4) =
            make_ushort4(lb16[q*4], lb16[q*4+1], lb16[q*4+2], lb16[q*4+3]);
    }
    atomicAdd(&x2a[rowidx], s2);
}

__global__ __launch_bounds__(256) void yat_attention5_kernel(
    const float* __restrict__ qkvT, const float* __restrict__ k2k,
    const float* __restrict__ alphap,
    unsigned short* __restrict__ attn_h, unsigned short* __restrict__ attn_l,
    float* __restrict__ x2a)
{
    // per-wave region: ktile 1024 f | vtile 1024 f | k2tile 64 f = 2112 f
    // merge buffer (3*64*37 = 7104 f) aliases tile regions post-barrier
    __shared__ __align__(16) float smem[8448];

    const int tid  = threadIdx.x;
    const int lane = tid & 63;
    const int q    = tid >> 6;          // j-quarter 0..3
    const int tau  = blockIdx.x;        // 0..7
    const int d    = blockIdx.y;        // 0..63
    const int b    = blockIdx.z;

    const int iA = tau * 64 + lane;
    const int iB = (15 - tau) * 64 + lane;
    const int ntiles = 16 - tau;

    // log2e folded in: softmax runs in exp2 domain
    const float inv_scale =
        powf(64.0f / log1pf(64.0f), alphap[0]) * 1.44269504f;

    const size_t plane = 16384;
    const float* qpl = qkvT + (size_t)((b * 3 + 0) * 64 + d) * plane;
    const float* kpl = qkvT + (size_t)((b * 3 + 1) * 64 + d) * plane;
    const float* vpl = qkvT + (size_t)((b * 3 + 2) * 64 + d) * plane;
    const float* k2row = k2k + ((size_t)b << 16) + ((size_t)d << 10);

    float* ktile  = smem + q * 2112;
    float* vtile  = ktile + 1024;
    float* k2tile = vtile + 1024;

    float qa[16], qb[16];
    #pragma unroll
    for (int h = 0; h < 16; ++h) {
        qa[h] = qpl[h * 1024 + iA];
        qb[h] = qpl[h * 1024 + iB];
    }
    float q2ea = YAT_EPS, q2eb = YAT_EPS;
    #pragma unroll
    for (int h = 0; h < 16; ++h) {
        q2ea = fmaf(qa[h], qa[h], q2ea);
        q2eb = fmaf(qb[h], qb[h], q2eb);
    }

    float mA = -1e30f, lA = 0.0f, mB = -1e30f, lB = 0.0f;
    float oa[16], ob[16];
    #pragma unroll
    for (int h = 0; h < 16; ++h) { oa[h] = 0.0f; ob[h] = 0.0f; }

    for (int jt = q; jt < ntiles; jt += 4) {
        const int j0 = jt * 64;
        // stage: lane <-> row j0+lane; 16 coalesced loads per array,
        // then 4 ds_write_b128 per array (2-way banks = free)
        float kr0[16], vr0[16];
        #pragma unroll
        for (int h = 0; h < 16; ++h) {
            kr0[h] = kpl[h * 1024 + j0 + lane];
            vr0[h] = vpl[h * 1024 + j0 + lane];
        }
        #pragma unroll
        for (int h4 = 0; h4 < 4; ++h4) {
            *(float4*)(ktile + lane * 16 + h4 * 4) = make_float4(
                kr0[h4*4], kr0[h4*4+1], kr0[h4*4+2], kr0[h4*4+3]);
            *(float4*)(vtile + lane * 16 + h4 * 4) = make_float4(
                vr0[h4*4], vr0[h4*4+1], vr0[h4*4+2], vr0[h4*4+3]);
        }
        k2tile[lane] = k2row[j0 + lane];
        // wave-private LDS: compiler inserts lgkm wait; no barrier needed
        if (jt <= tau)
            yat_tile<true>(ktile, vtile, k2tile, j0, iA, iB,
                           qa, qb, q2ea, q2eb, inv_scale,
                           mA, lA, oa, mB, lB, ob);
        else
            yat_tile<false>(ktile, vtile, k2tile, j0, iA, iB,
                            qa, qb, q2ea, q2eb, inv_scale,
                            mA, lA, oa, mB, lB, ob);
    }

    // ---- merge 4 quarters ----
    __syncthreads();
    if (q > 0) {
        float* mb = smem + ((q - 1) * 64 + lane) * 37;
        #pragma unroll
        for (int h = 0; h < 16; ++h) { mb[h] = oa[h]; mb[18 + h] = ob[h]; }
        mb[16] = mA; mb[17] = lA;
        mb[34] = mB; mb[35] = lB;
    }
    __syncthreads();
    if (q == 0) {
        #pragma unroll
        for (int qq = 0; qq < 3; ++qq) {
            const float* mb = smem + (qq * 64 + lane) * 37;
            float m1 = mb[16], l1 = mb[17];
            float m = fmaxf(mA, m1);
            float c0 = fast_exp2(mA - m), c1 = fast_exp2(m1 - m);
            lA = lA * c0 + l1 * c1;
            #pragma unroll
            for (int h = 0; h < 16; ++h) oa[h] = oa[h] * c0 + mb[h] * c1;
            mA = m;
            m1 = mb[34]; l1 = mb[35];
            m = fmaxf(mB, m1);
            c0 = fast_exp2(mB - m); c1 = fast_exp2(m1 - m);
            lB = lB * c0 + l1 * c1;
            #pragma unroll
            for (int h = 0; h < 16; ++h) ob[h] = ob[h] * c0 + mb[18 + h] * c1;
            mB = m;
        }
        const int rowA = b * 1024 + iA;
        const int rowB = b * 1024 + iB;
        write_row_hl(attn_h, attn_l, x2a, rowA,
                     (size_t)rowA * 1024 + d * 16, oa, 1.0f / lA);
        write_row_hl(attn_h, attn_l, x2a, rowB,
                     (size_t)rowB * 1024 + d * 16, ob, 1.0f / lB);
    }
}

// ---------------------------------------------------------------------------
extern "C" void kernel_launch(void* const* d_in, const int* in_sizes, int n_in,
                              void* d_out, int out_size, void* d_ws, size_t ws_size,
                              hipStream_t stream)
{
    const float* x          = (const float*)d_in[0];
    // d_in[1] = causal mask, constant — causality hard-coded
    const float* w_qkv      = (const float*)d_in[2];
    const float* b_qkv      = (const float*)d_in[3];
    const float* alpha_qkv  = (const float*)d_in[4];
    const float* w_proj     = (const float*)d_in[5];
    const float* b_proj     = (const float*)d_in[6];
    const float* alpha_proj = (const float*)d_in[7];
    const float* alpha_attn = (const float*)d_in[8];
    float* out = (float*)d_out;

    float* ws = (float*)d_ws;
    float*          qkvT = ws;                                   // 6291456
    unsigned short* WtQh = (unsigned short*)(ws + 6291456);      // 3072x1024 bf16
    unsigned short* WtQl = (unsigned short*)(ws + 7864320);
    unsigned short* WtPh = (unsigned short*)(ws + 9437184);      // 1024x1024 bf16
    unsigned short* WtPl = (unsigned short*)(ws + 9961472);
    unsigned short* xh   = (unsigned short*)(ws + 10485760);     // 2048x1024 bf16
    unsigned short* xl   = (unsigned short*)(ws + 11534336);
    float* x2x  = ws + 12582912;   // 2048
    float* x2a  = ws + 12584960;   // 2048 (atomic)
    float* k2q  = ws + 12587008;   // 3072 (atomic)
    float* k2p  = ws + 12590080;   // 1024 (atomic)
    float* k2k  = ws + 12591104;   // 131072
    unsigned short* attn_h = WtQh;  // alias: WtQ dead after QKV GEMM
    unsigned short* attn_l = WtQl;

    hipMemsetAsync(x2a, 0, (2048 + 3072 + 1024) * sizeof(float), stream);

    convtrans_kernel<<<dim3(96, 32), dim3(32, 8), 0, stream>>>(
        w_qkv, WtQh, WtQl, k2q, 1024, 3072);
    convtrans_kernel<<<dim3(32, 32), dim3(32, 8), 0, stream>>>(
        w_proj, WtPh, WtPl, k2p, 1024, 1024);
    convx_kernel<<<2048, 256, 0, stream>>>(x, xh, xl, x2x);

    const float sb_qkv = sqrtf(3072.0f) / log1pf(3072.0f);
    gemm_yat_mfma_kernel<128, 1><<<dim3(24, 16), 256, 0, stream>>>(
        xh, xl, WtQh, WtQl, b_qkv, x2x, k2q, alpha_qkv, qkvT,
        3072, 1024, sb_qkv);

    sumsq16_kernel<<<512, 256, 0, stream>>>(qkvT, k2k);

    yat_attention5_kernel<<<dim3(8, 64, 2), 256, 0, stream>>>(
        qkvT, k2k, alpha_attn, attn_h, attn_l, x2a);

    const float sb_proj = sqrtf(1024.0f) / log1pf(1024.0f);
    gemm_yat_mfma_kernel<64, 0><<<dim3(8, 32), 256, 0, stream>>>(
        attn_h, attn_l, WtPh, WtPl, b_proj, x2a, k2p, alpha_proj, out,
        1024, 1024, sb_proj);
}